// Round 1
// baseline (754.157 us; speedup 1.0000x reference)
//
#include <hip/hip_runtime.h>

// ---------------------------------------------------------------------------
// LSTMDecoder: 3 chained LSTM cells + edge FC + 3-head attention + heads.
// B=1024, H=768, S=256, C=(202,183,11).
// Strategy: bf16 MFMA GEMMs. LSTM-path GEMMs use 3-pass hi/lo split for
// ~fp32 precision (protects softmax scores). Attention fused single-pass
// fp32 (unnormalized exp; values kept in registers between phases).
// ---------------------------------------------------------------------------

typedef short  s16x8 __attribute__((ext_vector_type(8)));
typedef float  f32x4 __attribute__((ext_vector_type(4)));

__device__ __forceinline__ unsigned short f2bf(float f) {
  union { float f; unsigned int u; } x; x.f = f;
  unsigned int r = x.u + 0x7fffu + ((x.u >> 16) & 1u);
  return (unsigned short)(r >> 16);
}
__device__ __forceinline__ float bf2f(unsigned short u) {
  union { unsigned int u; float f; } x; x.u = ((unsigned int)u) << 16;
  return x.f;
}
__device__ __forceinline__ float sigm(float x) { return 1.f / (1.f + expf(-x)); }

// ---------------------------------------------------------------------------
// GEMM: out[M=1024][N] = A[1024xK] * W[NxK]^T (+bias)(+bias2)(+addend)(relu)
// A,W bf16 (optional lo-halves for 3-pass split). 128x128 tile, BK=32,
// 4 waves of 4x4 16x16x32 MFMA fragments.
// ---------------------------------------------------------------------------
__global__ __launch_bounds__(256)
void gemm_k(const unsigned short* __restrict__ Ah, const unsigned short* __restrict__ Al,
            const unsigned short* __restrict__ Wh, const unsigned short* __restrict__ Wl,
            float* __restrict__ outf, unsigned short* __restrict__ outbh,
            unsigned short* __restrict__ outbl,
            const float* __restrict__ bias, const float* __restrict__ bias2,
            const float* __restrict__ addend,
            int N, int K, int ldc, int relu)
{
  __shared__ unsigned short As[2][128 * 32];
  __shared__ unsigned short Bs[2][128 * 32];
  const int tid  = threadIdx.x;
  const int lane = tid & 63;
  const int wv   = tid >> 6;
  const int wm   = (wv >> 1) * 64;
  const int wn   = (wv & 1) * 64;
  const int bm0  = blockIdx.y * 128;
  const int bn0  = blockIdx.x * 128;
  const bool split = (Al != nullptr);

  const int i0 = tid, i1 = tid + 256;
  const int ar0 = bm0 + (i0 >> 2), ac0 = (i0 & 3) * 8;
  const int ar1 = bm0 + (i1 >> 2), ac1 = (i1 & 3) * 8;
  int br0 = bn0 + (i0 >> 2); if (br0 > N - 1) br0 = N - 1;
  int br1 = bn0 + (i1 >> 2); if (br1 > N - 1) br1 = N - 1;

  const int frow = lane & 15;
  const int fk   = (lane >> 4) * 8;

  f32x4 acc[4][4];
#pragma unroll
  for (int m = 0; m < 4; ++m)
#pragma unroll
    for (int n = 0; n < 4; ++n) acc[m][n] = (f32x4){0.f, 0.f, 0.f, 0.f};

  for (int k0 = 0; k0 < K; k0 += 32) {
    s16x8 avh0 = *(const s16x8*)(Ah + (size_t)ar0 * K + k0 + ac0);
    s16x8 avh1 = *(const s16x8*)(Ah + (size_t)ar1 * K + k0 + ac1);
    s16x8 bvh0 = *(const s16x8*)(Wh + (size_t)br0 * K + k0 + ac0);
    s16x8 bvh1 = *(const s16x8*)(Wh + (size_t)br1 * K + k0 + ac1);
    s16x8 avl0 = {}, avl1 = {}, bvl0 = {}, bvl1 = {};
    if (split) {
      avl0 = *(const s16x8*)(Al + (size_t)ar0 * K + k0 + ac0);
      avl1 = *(const s16x8*)(Al + (size_t)ar1 * K + k0 + ac1);
      bvl0 = *(const s16x8*)(Wl + (size_t)br0 * K + k0 + ac0);
      bvl1 = *(const s16x8*)(Wl + (size_t)br1 * K + k0 + ac1);
    }
    __syncthreads();
    *(s16x8*)(&As[0][i0 * 8]) = avh0;
    *(s16x8*)(&As[0][i1 * 8]) = avh1;
    *(s16x8*)(&Bs[0][i0 * 8]) = bvh0;
    *(s16x8*)(&Bs[0][i1 * 8]) = bvh1;
    if (split) {
      *(s16x8*)(&As[1][i0 * 8]) = avl0;
      *(s16x8*)(&As[1][i1 * 8]) = avl1;
      *(s16x8*)(&Bs[1][i0 * 8]) = bvl0;
      *(s16x8*)(&Bs[1][i1 * 8]) = bvl1;
    }
    __syncthreads();
    s16x8 ah[4], bh[4];
#pragma unroll
    for (int m = 0; m < 4; ++m)
      ah[m] = *(const s16x8*)(&As[0][(wm + m * 16 + frow) * 32 + fk]);
#pragma unroll
    for (int n = 0; n < 4; ++n)
      bh[n] = *(const s16x8*)(&Bs[0][(wn + n * 16 + frow) * 32 + fk]);
#pragma unroll
    for (int m = 0; m < 4; ++m)
#pragma unroll
      for (int n = 0; n < 4; ++n)
        acc[m][n] = __builtin_amdgcn_mfma_f32_16x16x32_bf16(ah[m], bh[n], acc[m][n], 0, 0, 0);
    if (split) {
      s16x8 xl[4];
#pragma unroll
      for (int m = 0; m < 4; ++m)
        xl[m] = *(const s16x8*)(&As[1][(wm + m * 16 + frow) * 32 + fk]);
#pragma unroll
      for (int m = 0; m < 4; ++m)
#pragma unroll
        for (int n = 0; n < 4; ++n)
          acc[m][n] = __builtin_amdgcn_mfma_f32_16x16x32_bf16(xl[m], bh[n], acc[m][n], 0, 0, 0);
#pragma unroll
      for (int n = 0; n < 4; ++n)
        xl[n] = *(const s16x8*)(&Bs[1][(wn + n * 16 + frow) * 32 + fk]);
#pragma unroll
      for (int m = 0; m < 4; ++m)
#pragma unroll
        for (int n = 0; n < 4; ++n)
          acc[m][n] = __builtin_amdgcn_mfma_f32_16x16x32_bf16(ah[m], xl[n], acc[m][n], 0, 0, 0);
    }
  }
  // epilogue: D layout col=lane&15, row=(lane>>4)*4+reg  [m89-verified]
  const int rb = (lane >> 4) * 4;
  const int c0 = lane & 15;
#pragma unroll
  for (int n = 0; n < 4; ++n) {
    const int col = bn0 + wn + n * 16 + c0;
    if (col >= N) continue;
    float bv = 0.f;
    if (bias)  bv += bias[col];
    if (bias2) bv += bias2[col];
#pragma unroll
    for (int m = 0; m < 4; ++m) {
      const int row0 = bm0 + wm + m * 16 + rb;
#pragma unroll
      for (int r = 0; r < 4; ++r) {
        const int row = row0 + r;
        float v = acc[m][n][r] + bv;
        if (addend) v += addend[(size_t)row * ldc + col];
        if (relu)   v = fmaxf(v, 0.f);
        if (outf)   outf[(size_t)row * ldc + col] = v;
        if (outbh) {
          unsigned short hb = f2bf(v);
          outbh[(size_t)row * ldc + col] = hb;
          if (outbl) outbl[(size_t)row * ldc + col] = f2bf(v - bf2f(hb));
        }
      }
    }
  }
}

// ---------------------------------------------------------------------------
// fp32 -> bf16(hi[,lo]) converter, multi-segment in one launch
// ---------------------------------------------------------------------------
struct CvtArgs {
  const float*    src[9];
  unsigned short* dsth[9];
  unsigned short* dstl[9];
  int n[9];
  int pfx[10];
};

__global__ __launch_bounds__(256)
void cvt_k(CvtArgs a)
{
  int blk = blockIdx.x, s = 0;
  while (s < 8 && blk >= a.pfx[s + 1]) ++s;
  int idx = ((blk - a.pfx[s]) * 256 + (int)threadIdx.x) * 4;
  if (idx >= a.n[s]) return;
  float4 v = *(const float4*)(a.src[s] + idx);
  ushort4 hi;
  hi.x = f2bf(v.x); hi.y = f2bf(v.y); hi.z = f2bf(v.z); hi.w = f2bf(v.w);
  *(ushort4*)(a.dsth[s] + idx) = hi;
  if (a.dstl[s]) {
    ushort4 lo;
    lo.x = f2bf(v.x - bf2f(hi.x)); lo.y = f2bf(v.y - bf2f(hi.y));
    lo.z = f2bf(v.z - bf2f(hi.z)); lo.w = f2bf(v.w - bf2f(hi.w));
    *(ushort4*)(a.dstl[s] + idx) = lo;
  }
}

// ---------------------------------------------------------------------------
// LSTM pointwise cells. G row stride 9216; task t gate block at col t*3072,
// order i,f,g,o (each 768 wide).
// ---------------------------------------------------------------------------
__global__ __launch_bounds__(256)
void lstm1_k(const float* __restrict__ G, float* h1f, float* c1f,
             unsigned short* h1bh, unsigned short* h1bl)
{
  int i = blockIdx.x * 256 + threadIdx.x;  // 0..786431
  int b = i / 768, j = i - b * 768;
  const float* g = G + (size_t)b * 9216;
  float c = sigm(g[j]) * tanhf(g[1536 + j]);          // c_prev = 0
  float h = sigm(g[2304 + j]) * tanhf(c);
  h1f[i] = h; c1f[i] = c;
  unsigned short hb = f2bf(h);
  h1bh[i] = hb; h1bl[i] = f2bf(h - bf2f(hb));
}

__global__ __launch_bounds__(256)
void lstm2_k(const float* __restrict__ G, const float* __restrict__ c1f,
             float* h2f, unsigned short* h2bh, unsigned short* h2bl,
             unsigned short* c2bh, unsigned short* c2bl)
{
  int i = blockIdx.x * 256 + threadIdx.x;
  int b = i / 768, j = i - b * 768;
  const float* g = G + (size_t)b * 9216;
  float c = sigm(g[3840 + j]) * c1f[i] + sigm(g[3072 + j]) * tanhf(g[4608 + j]);
  float h = sigm(g[5376 + j]) * tanhf(c);
  h2f[i] = h;
  unsigned short hb = f2bf(h);
  h2bh[i] = hb; h2bl[i] = f2bf(h - bf2f(hb));
  unsigned short cb = f2bf(c);
  c2bh[i] = cb; c2bl[i] = f2bf(c - bf2f(cb));
}

__global__ __launch_bounds__(256)
void lstm3_k(const float* __restrict__ G, const float* __restrict__ cp3f,
             float* h3f)
{
  int i = blockIdx.x * 256 + threadIdx.x;
  int b = i / 768, j = i - b * 768;
  const float* g = G + (size_t)b * 9216;
  float c = sigm(g[6912 + j]) * cp3f[i] + sigm(g[6144 + j]) * tanhf(g[7680 + j]);
  h3f[i] = sigm(g[8448 + j]) * tanhf(c);
}

// ---------------------------------------------------------------------------
// Fused attention for all 3 tasks. One block per batch row. Single pass over
// attn[b] (805 MB total): per 16-row tile, per-thread partial dots over its 3
// owned columns -> 64-lane shfl butterfly -> cross-wave combine in LDS ->
// unnormalized p = exp(score) -> accumulate with register-held values.
// ---------------------------------------------------------------------------
__global__ __launch_bounds__(256)
void attn_k(const float* __restrict__ attn,
            const float* __restrict__ h1, const float* __restrict__ h2,
            const float* __restrict__ h3,
            unsigned short* __restrict__ a1, unsigned short* __restrict__ a2,
            unsigned short* __restrict__ a3)
{
  const int b = blockIdx.x, t = threadIdx.x;
  const int lane = t & 63, wv = t >> 6;
  __shared__ float part[4][3][16];
  __shared__ float pbuf[3][16];
  const float* ab = attn + (size_t)b * 256 * 768;
  const int c0 = t, c1 = t + 256, c2 = t + 512;
  const float h00 = h1[b * 768 + c0], h01 = h1[b * 768 + c1], h02 = h1[b * 768 + c2];
  const float h10 = h2[b * 768 + c0], h11 = h2[b * 768 + c1], h12 = h2[b * 768 + c2];
  const float h20 = h3[b * 768 + c0], h21 = h3[b * 768 + c1], h22 = h3[b * 768 + c2];
  float acc[3][3] = {{0.f,0.f,0.f},{0.f,0.f,0.f},{0.f,0.f,0.f}};
  float l0 = 0.f, l1 = 0.f, l2 = 0.f;

  for (int tile = 0; tile < 16; ++tile) {
    const float* rp = ab + (size_t)tile * 16 * 768;
    float v0[16], v1[16], v2[16];
    float q0[16], q1[16], q2[16];
#pragma unroll
    for (int s = 0; s < 16; ++s) {
      const float* r = rp + s * 768;
      v0[s] = r[c0]; v1[s] = r[c1]; v2[s] = r[c2];
      q0[s] = v0[s] * h00 + v1[s] * h01 + v2[s] * h02;
      q1[s] = v0[s] * h10 + v1[s] * h11 + v2[s] * h12;
      q2[s] = v0[s] * h20 + v1[s] * h21 + v2[s] * h22;
    }
#pragma unroll
    for (int s = 0; s < 16; ++s) {
#pragma unroll
      for (int d = 1; d < 64; d <<= 1) {
        q0[s] += __shfl_xor(q0[s], d);
        q1[s] += __shfl_xor(q1[s], d);
        q2[s] += __shfl_xor(q2[s], d);
      }
    }
    if (lane == 0) {
#pragma unroll
      for (int s = 0; s < 16; ++s) {
        part[wv][0][s] = q0[s]; part[wv][1][s] = q1[s]; part[wv][2][s] = q2[s];
      }
    }
    __syncthreads();
    if (t < 48) {
      int i = t >> 4, s = t & 15;
      float sc = part[0][i][s] + part[1][i][s] + part[2][i][s] + part[3][i][s];
      pbuf[i][s] = expf(sc);   // scores bounded (|s| < ~35): fp32-safe unnormalized
    }
    __syncthreads();
#pragma unroll
    for (int s = 0; s < 16; ++s) {
      float p0 = pbuf[0][s], p1 = pbuf[1][s], p2 = pbuf[2][s];
      l0 += p0; l1 += p1; l2 += p2;
      acc[0][0] += p0 * v0[s]; acc[0][1] += p0 * v1[s]; acc[0][2] += p0 * v2[s];
      acc[1][0] += p1 * v0[s]; acc[1][1] += p1 * v1[s]; acc[1][2] += p1 * v2[s];
      acc[2][0] += p2 * v0[s]; acc[2][1] += p2 * v1[s]; acc[2][2] += p2 * v2[s];
    }
  }
  const float r0 = 1.f / l0, r1 = 1.f / l1, r2 = 1.f / l2;
  a1[b * 768 + c0] = f2bf(acc[0][0] * r0);
  a1[b * 768 + c1] = f2bf(acc[0][1] * r0);
  a1[b * 768 + c2] = f2bf(acc[0][2] * r0);
  a2[b * 768 + c0] = f2bf(acc[1][0] * r1);
  a2[b * 768 + c1] = f2bf(acc[1][1] * r1);
  a2[b * 768 + c2] = f2bf(acc[1][2] * r1);
  a3[b * 768 + c0] = f2bf(acc[2][0] * r2);
  a3[b * 768 + c1] = f2bf(acc[2][1] * r2);
  a3[b * 768 + c2] = f2bf(acc[2][2] * r2);
}

// ---------------------------------------------------------------------------
extern "C" void kernel_launch(void* const* d_in, const int* in_sizes, int n_in,
                              void* d_out, int out_size, void* d_ws, size_t ws_size,
                              hipStream_t stream)
{
  const float* x    = (const float*)d_in[0];
  const float* attn = (const float*)d_in[1];
  const float* Wih  = (const float*)d_in[2];
  const float* Whh  = (const float*)d_in[3];
  const float* bih  = (const float*)d_in[4];
  const float* bhh  = (const float*)d_in[5];
  const float* hfcW = (const float*)d_in[6];
  const float* hfcb = (const float*)d_in[7];
  const float* cfcW = (const float*)d_in[8];
  const float* cfcb = (const float*)d_in[9];
  const float* midW = (const float*)d_in[10];
  const float* midb = (const float*)d_in[11];
  const float* o1W  = (const float*)d_in[12];
  const float* o1b  = (const float*)d_in[13];
  const float* o2W  = (const float*)d_in[14];
  const float* o2b  = (const float*)d_in[15];
  const float* o3W  = (const float*)d_in[16];
  const float* o3b  = (const float*)d_in[17];
  float* out = (float*)d_out;
  char*  ws  = (char*)d_ws;

  float*          G     = (float*)(ws + 0);            // 1024 x 9216
  float*          h1f   = (float*)(ws + 37748736);
  float*          c1f   = (float*)(ws + 40894464);
  float*          h2f   = (float*)(ws + 44040192);
  float*          cp3f  = (float*)(ws + 47185920);
  float*          h3f   = (float*)(ws + 50331648);
  unsigned short* xbh   = (unsigned short*)(ws + 53477376);
  unsigned short* xbl   = (unsigned short*)(ws + 55050240);
  unsigned short* Wihh  = (unsigned short*)(ws + 56623104);
  unsigned short* Wihl  = (unsigned short*)(ws + 70778880);
  unsigned short* Whhh  = (unsigned short*)(ws + 84934656);
  unsigned short* Whhl  = (unsigned short*)(ws + 94371840);
  unsigned short* hfch  = (unsigned short*)(ws + 103809024);
  unsigned short* hfcl  = (unsigned short*)(ws + 104988672);
  unsigned short* cfch  = (unsigned short*)(ws + 106168320);
  unsigned short* cfcl  = (unsigned short*)(ws + 107347968);
  unsigned short* midWb = (unsigned short*)(ws + 108527616);
  unsigned short* o1Wb  = (unsigned short*)(ws + 112066560);
  unsigned short* o2Wb  = (unsigned short*)(ws + 112376832);
  unsigned short* o3Wb  = (unsigned short*)(ws + 112657920);
  unsigned short* h1bh  = (unsigned short*)(ws + 112674816);
  unsigned short* h1bl  = (unsigned short*)(ws + 114247680);
  unsigned short* h2bh  = (unsigned short*)(ws + 115820544);
  unsigned short* h2bl  = (unsigned short*)(ws + 117393408);
  unsigned short* c2bh  = (unsigned short*)(ws + 118966272);
  unsigned short* c2bl  = (unsigned short*)(ws + 120539136);
  unsigned short* hp3h  = (unsigned short*)(ws + 122112000);
  unsigned short* hp3l  = (unsigned short*)(ws + 123684864);
  unsigned short* a1b   = (unsigned short*)(ws + 125257728);
  unsigned short* a2b   = (unsigned short*)(ws + 126830592);
  unsigned short* a3b   = (unsigned short*)(ws + 128403456);
  unsigned short* m1b   = (unsigned short*)(ws + 129976320);
  unsigned short* m2b   = (unsigned short*)(ws + 131549184);
  unsigned short* m3b   = (unsigned short*)(ws + 133122048);
  // workspace end: 134,694,912 bytes (~128.5 MB)

  // ---- 1. convert weights/x to bf16 (hi/lo for LSTM-path operands) ----
  CvtArgs ca;
  const float*    srcs[9] = { x, Wih, Whh + 2359296, hfcW, cfcW, midW, o1W, o2W, o3W };
  unsigned short* dhs[9]  = { xbh, Wihh, Whhh, hfch, cfch, midWb, o1Wb, o2Wb, o3Wb };
  unsigned short* dls[9]  = { xbl, Wihl, Whhl, hfcl, cfcl, nullptr, nullptr, nullptr, nullptr };
  int ns[9] = { 786432, 7077888, 4718592, 589824, 589824, 1769472, 155136, 140544, 8448 };
  int pfx = 0;
  for (int i = 0; i < 9; ++i) {
    ca.src[i] = srcs[i]; ca.dsth[i] = dhs[i]; ca.dstl[i] = dls[i]; ca.n[i] = ns[i];
    ca.pfx[i] = pfx; pfx += (ns[i] + 1023) / 1024;
  }
  ca.pfx[9] = pfx;
  cvt_k<<<pfx, 256, 0, stream>>>(ca);

  // ---- 2. all-task input gates: G = x*Wih^T + bih + bhh  (split) ----
  gemm_k<<<dim3(72, 8), 256, 0, stream>>>(xbh, xbl, Wihh, Wihl,
      G, nullptr, nullptr, bih, bhh, nullptr, 9216, 768, 9216, 0);
  // ---- 3. LSTM cell 1 (zero state) ----
  lstm1_k<<<3072, 256, 0, stream>>>(G, h1f, c1f, h1bh, h1bl);
  // ---- 4. G[task1] += h1*Whh1^T  (split, in-place) ----
  gemm_k<<<dim3(24, 8), 256, 0, stream>>>(h1bh, h1bl, Whhh, Whhl,
      G + 3072, nullptr, nullptr, nullptr, nullptr, G + 3072, 3072, 768, 9216, 0);
  // ---- 5. LSTM cell 2 ----
  lstm2_k<<<3072, 256, 0, stream>>>(G, c1f, h2f, h2bh, h2bl, c2bh, c2bl);
  // ---- 6. hp3 = h1 + h2*hfcW^T + hfcb  (split; bf16 hi/lo out) ----
  gemm_k<<<dim3(6, 8), 256, 0, stream>>>(h2bh, h2bl, hfch, hfcl,
      nullptr, hp3h, hp3l, hfcb, nullptr, h1f, 768, 768, 768, 0);
  // ---- 7. cp3 = c1 + c2*cfcW^T + cfcb  (split; fp32 out) ----
  gemm_k<<<dim3(6, 8), 256, 0, stream>>>(c2bh, c2bl, cfch, cfcl,
      cp3f, nullptr, nullptr, cfcb, nullptr, c1f, 768, 768, 768, 0);
  // ---- 8. G[task2] += hp3*Whh2^T  (split, in-place) ----
  gemm_k<<<dim3(24, 8), 256, 0, stream>>>(hp3h, hp3l, Whhh + 2359296, Whhl + 2359296,
      G + 6144, nullptr, nullptr, nullptr, nullptr, G + 6144, 3072, 768, 9216, 0);
  // ---- 9. LSTM cell 3 ----
  lstm3_k<<<3072, 256, 0, stream>>>(G, cp3f, h3f);
  // ---- 10. fused attention (3 tasks, single pass over attn) ----
  attn_k<<<1024, 256, 0, stream>>>(attn, h1f, h2f, h3f, a1b, a2b, a3b);
  // ---- 11. heads: m = relu(a*midW^T + midb)  (plain bf16) ----
  gemm_k<<<dim3(6, 8), 256, 0, stream>>>(a1b, nullptr, midWb, nullptr,
      nullptr, m1b, nullptr, midb, nullptr, nullptr, 768, 768, 768, 1);
  gemm_k<<<dim3(6, 8), 256, 0, stream>>>(a2b, nullptr, midWb + 589824, nullptr,
      nullptr, m2b, nullptr, midb + 768, nullptr, nullptr, 768, 768, 768, 1);
  gemm_k<<<dim3(6, 8), 256, 0, stream>>>(a3b, nullptr, midWb + 1179648, nullptr,
      nullptr, m3b, nullptr, midb + 1536, nullptr, nullptr, 768, 768, 768, 1);
  // ---- 12. output heads ----
  gemm_k<<<dim3(2, 8), 256, 0, stream>>>(m1b, nullptr, o1Wb, nullptr,
      out, nullptr, nullptr, o1b, nullptr, nullptr, 202, 768, 202, 0);
  gemm_k<<<dim3(2, 8), 256, 0, stream>>>(m2b, nullptr, o2Wb, nullptr,
      out + 206848, nullptr, nullptr, o2b, nullptr, nullptr, 183, 768, 183, 0);
  gemm_k<<<dim3(1, 8), 256, 0, stream>>>(m3b, nullptr, o3Wb, nullptr,
      out + 394240, nullptr, nullptr, o3b, nullptr, nullptr, 11, 768, 11, 0);

  (void)in_sizes; (void)n_in; (void)out_size; (void)ws_size;
}

// Round 2
// 408.435 us; speedup vs baseline: 1.8465x; 1.8465x over previous
//
#include <hip/hip_runtime.h>

// ---------------------------------------------------------------------------
// LSTMDecoder: 3 chained LSTM cells + edge FC + 3-head attention + heads.
// B=1024, H=768, S=256, C=(202,183,11).
// R2: fp16 single-pass MFMA GEMMs (11-bit mantissa: gate err ~3e-4 ->
// score err ~3e-3, under 0.018 threshold with 4x margin). Attention:
// lane-owns-12-cols layout -> wave-local dots, 4-row subtiles (4x fewer
// shfl ops), one end-of-kernel LDS combine. GEMM LDS XOR-swizzled.
// ---------------------------------------------------------------------------

typedef unsigned short u16x8 __attribute__((ext_vector_type(8)));
typedef _Float16       f16x8 __attribute__((ext_vector_type(8)));
typedef float          f32x4 __attribute__((ext_vector_type(4)));

__device__ __forceinline__ unsigned short f2h(float f) {
  _Float16 h = (_Float16)f;
  return __builtin_bit_cast(unsigned short, h);
}
__device__ __forceinline__ float sigm(float x) { return 1.f / (1.f + expf(-x)); }

// ---------------------------------------------------------------------------
// GEMM: out[1024][N] = A[1024xK] * W[NxK]^T (+bias)(+bias2)(+addend)(relu)
// fp16 operands, fp32 accum. 128x128 tile, BK=32, 4 waves x (4x4) 16x16x32.
// Up to 3 jobs batched via blockIdx.z. LDS slots XOR-swizzled by (row&3).
// ---------------------------------------------------------------------------
struct GJob {
  const unsigned short* A; const unsigned short* W;
  float* outf; unsigned short* outh;
  const float* bias; const float* bias2; const float* addend;
  int N; int ldc; int relu;
};
struct GArgs { GJob j[3]; };

__global__ __launch_bounds__(256)
void gemm_k(GArgs P, int K)
{
  const GJob jb = P.j[blockIdx.z];
  const int bn0 = blockIdx.x * 128;
  if (bn0 >= jb.N) return;
  const int bm0 = blockIdx.y * 128;

  __shared__ unsigned short As[128 * 32];
  __shared__ unsigned short Bs[128 * 32];

  const int tid  = threadIdx.x;
  const int lane = tid & 63;
  const int wv   = tid >> 6;
  const int wm   = (wv >> 1) * 64;
  const int wn   = (wv & 1) * 64;

  // staging: chunk i covers (row=i>>2, logical slot=i&3) of the 128x32 tile;
  // physical slot = slot ^ (row&3)  (bank-conflict swizzle)
  const int i0 = tid, i1 = tid + 256;
  const int sr0 = i0 >> 2, sc0 = i0 & 3, sp0 = sc0 ^ (sr0 & 3);
  const int sr1 = i1 >> 2, sc1 = i1 & 3, sp1 = sc1 ^ (sr1 & 3);
  const int ar0 = bm0 + sr0, ar1 = bm0 + sr1;
  int br0 = bn0 + sr0; if (br0 >= jb.N) br0 = jb.N - 1;
  int br1 = bn0 + sr1; if (br1 >= jb.N) br1 = jb.N - 1;

  const int frow = lane & 15;
  const int fsl  = lane >> 4;                 // logical k-slot 0..3
  const int px   = (fsl ^ (frow & 3)) * 8;    // swizzled element offset

  f32x4 acc[4][4];
#pragma unroll
  for (int m = 0; m < 4; ++m)
#pragma unroll
    for (int n = 0; n < 4; ++n) acc[m][n] = (f32x4){0.f, 0.f, 0.f, 0.f};

  for (int k0 = 0; k0 < K; k0 += 32) {
    u16x8 av0 = *(const u16x8*)(jb.A + (size_t)ar0 * K + k0 + sc0 * 8);
    u16x8 av1 = *(const u16x8*)(jb.A + (size_t)ar1 * K + k0 + sc1 * 8);
    u16x8 bv0 = *(const u16x8*)(jb.W + (size_t)br0 * K + k0 + sc0 * 8);
    u16x8 bv1 = *(const u16x8*)(jb.W + (size_t)br1 * K + k0 + sc1 * 8);
    __syncthreads();
    *(u16x8*)(&As[sr0 * 32 + sp0 * 8]) = av0;
    *(u16x8*)(&As[sr1 * 32 + sp1 * 8]) = av1;
    *(u16x8*)(&Bs[sr0 * 32 + sp0 * 8]) = bv0;
    *(u16x8*)(&Bs[sr1 * 32 + sp1 * 8]) = bv1;
    __syncthreads();
    f16x8 ah[4], bh[4];
#pragma unroll
    for (int m = 0; m < 4; ++m)
      ah[m] = *(const f16x8*)(&As[(wm + m * 16 + frow) * 32 + px]);
#pragma unroll
    for (int n = 0; n < 4; ++n)
      bh[n] = *(const f16x8*)(&Bs[(wn + n * 16 + frow) * 32 + px]);
#pragma unroll
    for (int m = 0; m < 4; ++m)
#pragma unroll
      for (int n = 0; n < 4; ++n)
        acc[m][n] = __builtin_amdgcn_mfma_f32_16x16x32_f16(ah[m], bh[n], acc[m][n], 0, 0, 0);
  }

  // epilogue: C/D layout col=lane&15, row=(lane>>4)*4+reg  [m89-verified]
  const int rb = (lane >> 4) * 4;
  const int c0 = lane & 15;
#pragma unroll
  for (int n = 0; n < 4; ++n) {
    const int col = bn0 + wn + n * 16 + c0;
    if (col >= jb.N) continue;
    float bv = 0.f;
    if (jb.bias)  bv += jb.bias[col];
    if (jb.bias2) bv += jb.bias2[col];
#pragma unroll
    for (int m = 0; m < 4; ++m) {
      const int row0 = bm0 + wm + m * 16 + rb;
#pragma unroll
      for (int r = 0; r < 4; ++r) {
        const int row = row0 + r;
        float v = acc[m][n][r] + bv;
        if (jb.addend) v += jb.addend[(size_t)row * jb.ldc + col];
        if (jb.relu)   v = fmaxf(v, 0.f);
        if (jb.outf)   jb.outf[(size_t)row * jb.ldc + col] = v;
        if (jb.outh)   jb.outh[(size_t)row * jb.ldc + col] = f2h(v);
      }
    }
  }
}

// ---------------------------------------------------------------------------
// fp32 -> fp16 converter, multi-segment in one launch
// ---------------------------------------------------------------------------
struct CvtArgs {
  const float*    src[9];
  unsigned short* dst[9];
  int n[9];
  int pfx[10];
};

__global__ __launch_bounds__(256)
void cvt_k(CvtArgs a)
{
  int blk = blockIdx.x, s = 0;
  while (s < 8 && blk >= a.pfx[s + 1]) ++s;
  int idx = ((blk - a.pfx[s]) * 256 + (int)threadIdx.x) * 4;
  if (idx >= a.n[s]) return;
  float4 v = *(const float4*)(a.src[s] + idx);
  ushort4 h;
  h.x = f2h(v.x); h.y = f2h(v.y); h.z = f2h(v.z); h.w = f2h(v.w);
  *(ushort4*)(a.dst[s] + idx) = h;
}

// ---------------------------------------------------------------------------
// LSTM pointwise cells. G row stride 9216; task t gate block at col t*3072,
// order i,f,g,o (each 768 wide).
// ---------------------------------------------------------------------------
__global__ __launch_bounds__(256)
void lstm1_k(const float* __restrict__ G, float* h1f, float* c1f, unsigned short* h1h)
{
  int i = blockIdx.x * 256 + threadIdx.x;
  int b = i / 768, j = i - b * 768;
  const float* g = G + (size_t)b * 9216;
  float c = sigm(g[j]) * tanhf(g[1536 + j]);          // c_prev = 0
  float h = sigm(g[2304 + j]) * tanhf(c);
  h1f[i] = h; c1f[i] = c; h1h[i] = f2h(h);
}

__global__ __launch_bounds__(256)
void lstm2_k(const float* __restrict__ G, const float* __restrict__ c1f,
             float* h2f, unsigned short* h2h, unsigned short* c2h)
{
  int i = blockIdx.x * 256 + threadIdx.x;
  int b = i / 768, j = i - b * 768;
  const float* g = G + (size_t)b * 9216;
  float c = sigm(g[3840 + j]) * c1f[i] + sigm(g[3072 + j]) * tanhf(g[4608 + j]);
  float h = sigm(g[5376 + j]) * tanhf(c);
  h2f[i] = h; h2h[i] = f2h(h); c2h[i] = f2h(c);
}

__global__ __launch_bounds__(256)
void lstm3_k(const float* __restrict__ G, const float* __restrict__ cp3f, float* h3f)
{
  int i = blockIdx.x * 256 + threadIdx.x;
  int b = i / 768, j = i - b * 768;
  const float* g = G + (size_t)b * 9216;
  float c = sigm(g[6912 + j]) * cp3f[i] + sigm(g[6144 + j]) * tanhf(g[7680 + j]);
  h3f[i] = sigm(g[8448 + j]) * tanhf(c);
}

// ---------------------------------------------------------------------------
// Fused attention, all 3 tasks, single pass over attn (805 MB).
// Block = 4 waves; wave w owns rows [w*64, w*64+64); lane owns 12 columns
// (64 lanes x 12 = 768) so every dot product is wave-local (butterfly only,
// no cross-wave per-tile traffic). 4-row subtiles: 12 butterfly values each.
// Unnormalized exp (scores bounded, fp32-safe); one LDS combine at the end.
// ---------------------------------------------------------------------------
__global__ __launch_bounds__(256)
void attn_k(const float* __restrict__ attn,
            const float* __restrict__ h1, const float* __restrict__ h2,
            const float* __restrict__ h3,
            unsigned short* __restrict__ a1, unsigned short* __restrict__ a2,
            unsigned short* __restrict__ a3)
{
  const int b = blockIdx.x, tid = threadIdx.x;
  const int lane = tid & 63, wv = tid >> 6;
  __shared__ float accW[4][3][768];
  __shared__ float lsumW[4][3];

  const float* ab = attn + (size_t)b * 256 * 768;
  const int cbase = lane * 12;

  float4 hh[3][3];
  {
    const float* hp0 = h1 + b * 768 + cbase;
    const float* hp1 = h2 + b * 768 + cbase;
    const float* hp2 = h3 + b * 768 + cbase;
#pragma unroll
    for (int j = 0; j < 3; ++j) {
      hh[0][j] = *(const float4*)(hp0 + 4 * j);
      hh[1][j] = *(const float4*)(hp1 + 4 * j);
      hh[2][j] = *(const float4*)(hp2 + 4 * j);
    }
  }

  float4 acc[3][3];
#pragma unroll
  for (int t3 = 0; t3 < 3; ++t3)
#pragma unroll
    for (int j = 0; j < 3; ++j) acc[t3][j] = (float4){0.f, 0.f, 0.f, 0.f};
  float lsum[3] = {0.f, 0.f, 0.f};

  const int row0 = wv * 64;
  for (int sub = 0; sub < 16; ++sub) {
    const float* rp = ab + (size_t)(row0 + sub * 4) * 768 + cbase;
    float4 vv[4][3];
#pragma unroll
    for (int s = 0; s < 4; ++s)
#pragma unroll
      for (int j = 0; j < 3; ++j)
        vv[s][j] = *(const float4*)(rp + s * 768 + 4 * j);

    float q[3][4];
#pragma unroll
    for (int t3 = 0; t3 < 3; ++t3)
#pragma unroll
      for (int s = 0; s < 4; ++s) {
        float d = 0.f;
#pragma unroll
        for (int j = 0; j < 3; ++j) {
          d = fmaf(vv[s][j].x, hh[t3][j].x, d);
          d = fmaf(vv[s][j].y, hh[t3][j].y, d);
          d = fmaf(vv[s][j].z, hh[t3][j].z, d);
          d = fmaf(vv[s][j].w, hh[t3][j].w, d);
        }
        q[t3][s] = d;
      }
#pragma unroll
    for (int t3 = 0; t3 < 3; ++t3)
#pragma unroll
      for (int s = 0; s < 4; ++s) {
#pragma unroll
        for (int d = 1; d < 64; d <<= 1)
          q[t3][s] += __shfl_xor(q[t3][s], d);
        q[t3][s] = __expf(q[t3][s]);   // scores bounded; unnormalized exp safe
      }
#pragma unroll
    for (int t3 = 0; t3 < 3; ++t3)
#pragma unroll
      for (int s = 0; s < 4; ++s) {
        const float p = q[t3][s];
        lsum[t3] += p;
#pragma unroll
        for (int j = 0; j < 3; ++j) {
          acc[t3][j].x = fmaf(p, vv[s][j].x, acc[t3][j].x);
          acc[t3][j].y = fmaf(p, vv[s][j].y, acc[t3][j].y);
          acc[t3][j].z = fmaf(p, vv[s][j].z, acc[t3][j].z);
          acc[t3][j].w = fmaf(p, vv[s][j].w, acc[t3][j].w);
        }
      }
  }

#pragma unroll
  for (int t3 = 0; t3 < 3; ++t3)
#pragma unroll
    for (int j = 0; j < 3; ++j)
      *(float4*)(&accW[wv][t3][cbase + 4 * j]) = acc[t3][j];
  if (lane == 0) {
#pragma unroll
    for (int t3 = 0; t3 < 3; ++t3) lsumW[wv][t3] = lsum[t3];
  }
  __syncthreads();

  float ltot[3];
#pragma unroll
  for (int t3 = 0; t3 < 3; ++t3)
    ltot[t3] = lsumW[0][t3] + lsumW[1][t3] + lsumW[2][t3] + lsumW[3][t3];
  unsigned short* outs[3] = { a1, a2, a3 };
#pragma unroll
  for (int cc = 0; cc < 3; ++cc) {
    const int c = tid + cc * 256;
#pragma unroll
    for (int t3 = 0; t3 < 3; ++t3) {
      float s = accW[0][t3][c] + accW[1][t3][c] + accW[2][t3][c] + accW[3][t3][c];
      outs[t3][b * 768 + c] = f2h(s / ltot[t3]);
    }
  }
}

// ---------------------------------------------------------------------------
extern "C" void kernel_launch(void* const* d_in, const int* in_sizes, int n_in,
                              void* d_out, int out_size, void* d_ws, size_t ws_size,
                              hipStream_t stream)
{
  const float* x    = (const float*)d_in[0];
  const float* attn = (const float*)d_in[1];
  const float* Wih  = (const float*)d_in[2];
  const float* Whh  = (const float*)d_in[3];
  const float* bih  = (const float*)d_in[4];
  const float* bhh  = (const float*)d_in[5];
  const float* hfcW = (const float*)d_in[6];
  const float* hfcb = (const float*)d_in[7];
  const float* cfcW = (const float*)d_in[8];
  const float* cfcb = (const float*)d_in[9];
  const float* midW = (const float*)d_in[10];
  const float* midb = (const float*)d_in[11];
  const float* o1W  = (const float*)d_in[12];
  const float* o1b  = (const float*)d_in[13];
  const float* o2W  = (const float*)d_in[14];
  const float* o2b  = (const float*)d_in[15];
  const float* o3W  = (const float*)d_in[16];
  const float* o3b  = (const float*)d_in[17];
  float* out = (float*)d_out;
  char*  ws  = (char*)d_ws;

  float*          G    = (float*)(ws + 0);          // 1024 x 9216 fp32
  float*          h1f  = (float*)(ws + 37748736);
  float*          c1f  = (float*)(ws + 40894464);
  float*          h2f  = (float*)(ws + 44040192);
  float*          cp3f = (float*)(ws + 47185920);
  float*          h3f  = (float*)(ws + 50331648);
  unsigned short* xh   = (unsigned short*)(ws + 53477376);
  unsigned short* Wihh = (unsigned short*)(ws + 55050240);
  unsigned short* Whhh = (unsigned short*)(ws + 69206016);  // tasks 1,2 only
  unsigned short* hfch = (unsigned short*)(ws + 78643200);
  unsigned short* cfch = (unsigned short*)(ws + 79822848);
  unsigned short* midh = (unsigned short*)(ws + 81002496);
  unsigned short* o1h  = (unsigned short*)(ws + 84541440);
  unsigned short* o2h  = (unsigned short*)(ws + 84851712);
  unsigned short* o3h  = (unsigned short*)(ws + 85132800);
  unsigned short* h1h  = (unsigned short*)(ws + 85149696);
  unsigned short* h2h  = (unsigned short*)(ws + 86722560);
  unsigned short* c2h  = (unsigned short*)(ws + 88295424);
  unsigned short* hp3h = (unsigned short*)(ws + 89868288);
  unsigned short* a1h  = (unsigned short*)(ws + 91441152);
  unsigned short* a2h  = (unsigned short*)(ws + 93014016);
  unsigned short* a3h  = (unsigned short*)(ws + 94586880);
  unsigned short* m1h  = (unsigned short*)(ws + 96159744);
  unsigned short* m2h  = (unsigned short*)(ws + 97732608);
  unsigned short* m3h  = (unsigned short*)(ws + 99305472);
  // workspace end: 100,878,336 bytes

  // ---- 1. fp32 -> fp16 conversions ----
  CvtArgs ca;
  const float*    srcs[9] = { x, Wih, Whh + 2359296, hfcW, cfcW, midW, o1W, o2W, o3W };
  unsigned short* dsts[9] = { xh, Wihh, Whhh, hfch, cfch, midh, o1h, o2h, o3h };
  int ns[9] = { 786432, 7077888, 4718592, 589824, 589824, 1769472, 155136, 140544, 8448 };
  int pfx = 0;
  for (int i = 0; i < 9; ++i) {
    ca.src[i] = srcs[i]; ca.dst[i] = dsts[i]; ca.n[i] = ns[i];
    ca.pfx[i] = pfx; pfx += (ns[i] + 1023) / 1024;
  }
  ca.pfx[9] = pfx;
  cvt_k<<<pfx, 256, 0, stream>>>(ca);

  GArgs P;

  // ---- 2. all-task input gates: G = x*Wih^T + bih + bhh ----
  P = GArgs{};
  P.j[0] = { xh, Wihh, G, nullptr, bih, bhh, nullptr, 9216, 9216, 0 };
  gemm_k<<<dim3(72, 8, 1), 256, 0, stream>>>(P, 768);
  // ---- 3. LSTM cell 1 (zero state) ----
  lstm1_k<<<3072, 256, 0, stream>>>(G, h1f, c1f, h1h);
  // ---- 4. G[task1] += h1*Whh1^T ----
  P = GArgs{};
  P.j[0] = { h1h, Whhh, G + 3072, nullptr, nullptr, nullptr, G + 3072, 3072, 9216, 0 };
  gemm_k<<<dim3(24, 8, 1), 256, 0, stream>>>(P, 768);
  // ---- 5. LSTM cell 2 ----
  lstm2_k<<<3072, 256, 0, stream>>>(G, c1f, h2f, h2h, c2h);
  // ---- 6+7. hp3 = h1 + h2*hfcW^T + hfcb ; cp3 = c1 + c2*cfcW^T + cfcb ----
  P = GArgs{};
  P.j[0] = { h2h, hfch, nullptr, hp3h, hfcb, nullptr, h1f, 768, 768, 0 };
  P.j[1] = { c2h, cfch, cp3f, nullptr, cfcb, nullptr, c1f, 768, 768, 0 };
  gemm_k<<<dim3(6, 8, 2), 256, 0, stream>>>(P, 768);
  // ---- 8. G[task2] += hp3*Whh2^T ----
  P = GArgs{};
  P.j[0] = { hp3h, Whhh + 2359296, G + 6144, nullptr, nullptr, nullptr, G + 6144, 3072, 9216, 0 };
  gemm_k<<<dim3(24, 8, 1), 256, 0, stream>>>(P, 768);
  // ---- 9. LSTM cell 3 ----
  lstm3_k<<<3072, 256, 0, stream>>>(G, cp3f, h3f);
  // ---- 10. fused attention (single pass over attn) ----
  attn_k<<<1024, 256, 0, stream>>>(attn, h1f, h2f, h3f, a1h, a2h, a3h);
  // ---- 11. heads: m = relu(a*midW^T + midb), 3 tasks batched ----
  P = GArgs{};
  P.j[0] = { a1h, midh,           nullptr, m1h, midb,        nullptr, nullptr, 768, 768, 1 };
  P.j[1] = { a2h, midh +  589824, nullptr, m2h, midb +  768, nullptr, nullptr, 768, 768, 1 };
  P.j[2] = { a3h, midh + 1179648, nullptr, m3h, midb + 1536, nullptr, nullptr, 768, 768, 1 };
  gemm_k<<<dim3(6, 8, 3), 256, 0, stream>>>(P, 768);
  // ---- 12. output heads, 3 tasks batched ----
  P = GArgs{};
  P.j[0] = { m1h, o1h, out,          nullptr, o1b, nullptr, nullptr, 202, 202, 0 };
  P.j[1] = { m2h, o2h, out + 206848, nullptr, o2b, nullptr, nullptr, 183, 183, 0 };
  P.j[2] = { m3h, o3h, out + 394240, nullptr, o3b, nullptr, nullptr,  11,  11, 0 };
  gemm_k<<<dim3(2, 8, 3), 256, 0, stream>>>(P, 768);

  (void)in_sizes; (void)n_in; (void)out_size; (void)ws_size;
}

// Round 3
// 393.545 us; speedup vs baseline: 1.9163x; 1.0378x over previous
//
#include <hip/hip_runtime.h>

// ---------------------------------------------------------------------------
// LSTMDecoder: 3 chained LSTM cells + edge FC + 3-head attention + heads.
// B=1024, H=768, S=256, C=(202,183,11).
// R3: fp16 MFMA GEMMs with global_load_lds(16B) staging, bank-floor XOR
// swizzle (c ^ ((r+(r>>2))&3)) applied via pre-swizzled global source +
// swizzled ds_read. LSTM cells fused into GEMM epilogues (gate-stripe
// layout: block = 32 j-cols x 4 gates; wave = 32 rows x all gates so each
// thread owns i,f,g,o of its (row,j)). Attention: fused 3-task single
// fp32 pass, lane-owns-12-cols wave-local dots.
// ---------------------------------------------------------------------------

typedef unsigned short u16;
typedef unsigned short u16x8 __attribute__((ext_vector_type(8)));
typedef _Float16       f16x8 __attribute__((ext_vector_type(8)));
typedef float          f32x4 __attribute__((ext_vector_type(4)));

#define SWZ(r) ((((r) + ((r) >> 2))) & 3)

__device__ __forceinline__ u16 f2h(float f) {
  _Float16 h = (_Float16)f;
  return __builtin_bit_cast(u16, h);
}
__device__ __forceinline__ float sigm(float x) { return 1.f / (1.f + __expf(-x)); }
__device__ __forceinline__ float ftanh(float x) { return 1.f - 2.f / (__expf(2.f * x) + 1.f); }

__device__ __forceinline__ void gld16(const u16* g, u16* l) {
  __builtin_amdgcn_global_load_lds(
      (const __attribute__((address_space(1))) unsigned int*)(g),
      (__attribute__((address_space(3))) unsigned int*)(l),
      16, 0, 0);
}

// ---------------------------------------------------------------------------
// Plain GEMM: out[1024][N] = A[1024xK]*W[NxK]^T (+bias)(+bias2)(+addend)(relu)
// 128x128 tile, BK=32, 4 waves x (4x4) 16x16x32 f16 MFMA. z-batched jobs.
// ---------------------------------------------------------------------------
struct GJob {
  const u16* A; const u16* W;
  float* outf; u16* outh;
  const float* bias; const float* bias2; const float* addend;
  int N; int ldc; int relu;
};
struct GArgs { GJob j[3]; };

__global__ __launch_bounds__(256)
void gemm_k(GArgs P, int K)
{
  const GJob jb = P.j[blockIdx.z];
  const int bn0 = blockIdx.x * 128;
  if (bn0 >= jb.N) return;
  const int bm0 = blockIdx.y * 128;

  __shared__ __align__(16) u16 As[128 * 32];
  __shared__ __align__(16) u16 Bs[128 * 32];

  const int tid = threadIdx.x, lane = tid & 63, wv = tid >> 6;
  const int wm = (wv >> 1) * 64, wn = (wv & 1) * 64;

  // staging: chunk q = 16B; row r=q>>2, phys slot p=q&3 holds logical p^SWZ(r)
  const int q0 = tid, q1 = tid + 256;
  const int r0 = q0 >> 2, c0s = (q0 & 3) ^ SWZ(r0);
  const int r1 = q1 >> 2, c1s = (q1 & 3) ^ SWZ(r1);
  int br0 = bn0 + r0; if (br0 >= jb.N) br0 = jb.N - 1;
  int br1 = bn0 + r1; if (br1 >= jb.N) br1 = jb.N - 1;
  const u16* pa0 = jb.A + (size_t)(bm0 + r0) * K + c0s * 8;
  const u16* pa1 = jb.A + (size_t)(bm0 + r1) * K + c1s * 8;
  const u16* pb0 = jb.W + (size_t)br0 * K + c0s * 8;
  const u16* pb1 = jb.W + (size_t)br1 * K + c1s * 8;
  u16* lA0 = &As[wv * 512];  u16* lA1 = &As[2048 + wv * 512];
  u16* lB0 = &Bs[wv * 512];  u16* lB1 = &Bs[2048 + wv * 512];

  const int frow = lane & 15, fsl = lane >> 4;

  f32x4 acc[4][4];
#pragma unroll
  for (int m = 0; m < 4; ++m)
#pragma unroll
    for (int n = 0; n < 4; ++n) acc[m][n] = (f32x4){0.f, 0.f, 0.f, 0.f};

  for (int k0 = 0; k0 < K; k0 += 32) {
    gld16(pa0 + k0, lA0);
    gld16(pa1 + k0, lA1);
    gld16(pb0 + k0, lB0);
    gld16(pb1 + k0, lB1);
    __syncthreads();
    f16x8 ah[4], bh[4];
#pragma unroll
    for (int m = 0; m < 4; ++m) {
      const int ar = wm + m * 16 + frow;
      ah[m] = *(const f16x8*)(&As[ar * 32 + (fsl ^ SWZ(ar)) * 8]);
    }
#pragma unroll
    for (int n = 0; n < 4; ++n) {
      const int br = wn + n * 16 + frow;
      bh[n] = *(const f16x8*)(&Bs[br * 32 + (fsl ^ SWZ(br)) * 8]);
    }
#pragma unroll
    for (int m = 0; m < 4; ++m)
#pragma unroll
      for (int n = 0; n < 4; ++n)
        acc[m][n] = __builtin_amdgcn_mfma_f32_16x16x32_f16(ah[m], bh[n], acc[m][n], 0, 0, 0);
    __syncthreads();
  }

  // epilogue: C/D layout col=lane&15, row=(lane>>4)*4+reg  [m89-verified]
  const int rb = (lane >> 4) * 4;
  const int cc = lane & 15;
#pragma unroll
  for (int n = 0; n < 4; ++n) {
    const int col = bn0 + wn + n * 16 + cc;
    if (col >= jb.N) continue;
    float bv = 0.f;
    if (jb.bias)  bv += jb.bias[col];
    if (jb.bias2) bv += jb.bias2[col];
#pragma unroll
    for (int m = 0; m < 4; ++m) {
      const int row0 = bm0 + wm + m * 16 + rb;
#pragma unroll
      for (int r = 0; r < 4; ++r) {
        const int row = row0 + r;
        float v = acc[m][n][r] + bv;
        if (jb.addend) v += jb.addend[(size_t)row * jb.ldc + col];
        if (jb.relu)   v = fmaxf(v, 0.f);
        if (jb.outf)   jb.outf[(size_t)row * jb.ldc + col] = v;
        if (jb.outh)   jb.outh[(size_t)row * jb.ldc + col] = f2h(v);
      }
    }
  }
}

// ---------------------------------------------------------------------------
// Fused LSTM-cell GEMM: gates = A*W^T (+bih+bhh | +addend), then cell math
// in the epilogue. Block covers 128 rows x 32 j-cols (all 4 gates);
// B-tile row r_lds in [0,128) <-> W row (r_lds>>5)*768 + bj0 + (r_lds&31).
// Wave w: rows [w*32,w*32+32) x all 128 B-rows -> thread owns i,f,g,o.
// ---------------------------------------------------------------------------
__global__ __launch_bounds__(256)
void cell_k(const u16* __restrict__ A, const u16* __restrict__ W,
            const float* __restrict__ bi, const float* __restrict__ bh_,
            const float* __restrict__ addend, int lda,
            const float* __restrict__ cprev,
            float* __restrict__ hf, float* __restrict__ cf,
            u16* __restrict__ hh, u16* __restrict__ ch, int K)
{
  const int bj0 = blockIdx.x * 32;
  const int bm0 = blockIdx.y * 128;

  __shared__ __align__(16) u16 As[128 * 32];
  __shared__ __align__(16) u16 Bs[128 * 32];

  const int tid = threadIdx.x, lane = tid & 63, wv = tid >> 6;

  const int q0 = tid, q1 = tid + 256;
  const int r0 = q0 >> 2, c0s = (q0 & 3) ^ SWZ(r0);
  const int r1 = q1 >> 2, c1s = (q1 & 3) ^ SWZ(r1);
  const int wr0 = (r0 >> 5) * 768 + bj0 + (r0 & 31);
  const int wr1 = (r1 >> 5) * 768 + bj0 + (r1 & 31);
  const u16* pa0 = A + (size_t)(bm0 + r0) * K + c0s * 8;
  const u16* pa1 = A + (size_t)(bm0 + r1) * K + c1s * 8;
  const u16* pb0 = W + (size_t)wr0 * K + c0s * 8;
  const u16* pb1 = W + (size_t)wr1 * K + c1s * 8;
  u16* lA0 = &As[wv * 512];  u16* lA1 = &As[2048 + wv * 512];
  u16* lB0 = &Bs[wv * 512];  u16* lB1 = &Bs[2048 + wv * 512];

  const int frow = lane & 15, fsl = lane >> 4;

  f32x4 acc[2][8];
#pragma unroll
  for (int m = 0; m < 2; ++m)
#pragma unroll
    for (int n = 0; n < 8; ++n) acc[m][n] = (f32x4){0.f, 0.f, 0.f, 0.f};

  for (int k0 = 0; k0 < K; k0 += 32) {
    gld16(pa0 + k0, lA0);
    gld16(pa1 + k0, lA1);
    gld16(pb0 + k0, lB0);
    gld16(pb1 + k0, lB1);
    __syncthreads();
    f16x8 ah[2], bh8[8];
#pragma unroll
    for (int m = 0; m < 2; ++m) {
      const int ar = wv * 32 + m * 16 + frow;
      ah[m] = *(const f16x8*)(&As[ar * 32 + (fsl ^ SWZ(ar)) * 8]);
    }
#pragma unroll
    for (int n = 0; n < 8; ++n) {
      const int br = n * 16 + frow;
      bh8[n] = *(const f16x8*)(&Bs[br * 32 + (fsl ^ SWZ(br)) * 8]);
    }
#pragma unroll
    for (int m = 0; m < 2; ++m)
#pragma unroll
      for (int n = 0; n < 8; ++n)
        acc[m][n] = __builtin_amdgcn_mfma_f32_16x16x32_f16(ah[m], bh8[n], acc[m][n], 0, 0, 0);
    __syncthreads();
  }

  // epilogue: thread's n-frags n=gate*2+jj -> full i,f,g,o per (row,j)
  const int rb = (lane >> 4) * 4;
  const int cc = lane & 15;
#pragma unroll
  for (int jj = 0; jj < 2; ++jj) {
    const int j = bj0 + jj * 16 + cc;
    float b_i = 0.f, b_f = 0.f, b_g = 0.f, b_o = 0.f;
    if (bi) {
      b_i = bi[j]        + bh_[j];
      b_f = bi[768 + j]  + bh_[768 + j];
      b_g = bi[1536 + j] + bh_[1536 + j];
      b_o = bi[2304 + j] + bh_[2304 + j];
    }
#pragma unroll
    for (int m = 0; m < 2; ++m) {
      const int row0 = bm0 + wv * 32 + m * 16 + rb;
#pragma unroll
      for (int r = 0; r < 4; ++r) {
        const int row = row0 + r;
        float gi = acc[m][0 + jj][r] + b_i;
        float gf = acc[m][2 + jj][r] + b_f;
        float gg = acc[m][4 + jj][r] + b_g;
        float go = acc[m][6 + jj][r] + b_o;
        if (addend) {
          const float* ad = addend + (size_t)row * lda;
          gi += ad[j]; gf += ad[768 + j]; gg += ad[1536 + j]; go += ad[2304 + j];
        }
        float c = sigm(gi) * ftanh(gg);
        if (cprev) c += sigm(gf) * cprev[row * 768 + j];
        float h = sigm(go) * ftanh(c);
        if (hf) hf[row * 768 + j] = h;
        if (cf) cf[row * 768 + j] = c;
        if (hh) hh[row * 768 + j] = f2h(h);
        if (ch) ch[row * 768 + j] = f2h(c);
      }
    }
  }
}

// ---------------------------------------------------------------------------
// fp32 -> fp16 converter, multi-segment in one launch
// ---------------------------------------------------------------------------
struct CvtArgs {
  const float* src[9];
  u16*         dst[9];
  int n[9];
  int pfx[10];
};

__global__ __launch_bounds__(256)
void cvt_k(CvtArgs a)
{
  int blk = blockIdx.x, s = 0;
  while (s < 8 && blk >= a.pfx[s + 1]) ++s;
  int idx = ((blk - a.pfx[s]) * 256 + (int)threadIdx.x) * 4;
  if (idx >= a.n[s]) return;
  float4 v = *(const float4*)(a.src[s] + idx);
  ushort4 h;
  h.x = f2h(v.x); h.y = f2h(v.y); h.z = f2h(v.z); h.w = f2h(v.w);
  *(ushort4*)(a.dst[s] + idx) = h;
}

// ---------------------------------------------------------------------------
// Fused attention, all 3 tasks, single pass over attn (805 MB fp32).
// Block = 4 waves; wave w owns rows [w*64,w*64+64); lane owns 12 columns
// (64x12=768) so dots are wave-local. 4-row subtiles; unnormalized exp;
// one end-of-kernel LDS combine.
// ---------------------------------------------------------------------------
__global__ __launch_bounds__(256)
void attn_k(const float* __restrict__ attn,
            const float* __restrict__ h1, const float* __restrict__ h2,
            const float* __restrict__ h3,
            u16* __restrict__ a1, u16* __restrict__ a2, u16* __restrict__ a3)
{
  const int b = blockIdx.x, tid = threadIdx.x;
  const int lane = tid & 63, wv = tid >> 6;
  __shared__ float accW[4][3][768];
  __shared__ float lsumW[4][3];

  const float* ab = attn + (size_t)b * 256 * 768;
  const int cbase = lane * 12;

  float4 hh[3][3];
  {
    const float* hp0 = h1 + b * 768 + cbase;
    const float* hp1 = h2 + b * 768 + cbase;
    const float* hp2 = h3 + b * 768 + cbase;
#pragma unroll
    for (int j = 0; j < 3; ++j) {
      hh[0][j] = *(const float4*)(hp0 + 4 * j);
      hh[1][j] = *(const float4*)(hp1 + 4 * j);
      hh[2][j] = *(const float4*)(hp2 + 4 * j);
    }
  }

  float4 acc[3][3];
#pragma unroll
  for (int t3 = 0; t3 < 3; ++t3)
#pragma unroll
    for (int j = 0; j < 3; ++j) acc[t3][j] = (float4){0.f, 0.f, 0.f, 0.f};
  float lsum[3] = {0.f, 0.f, 0.f};

  const int row0 = wv * 64;
  for (int sub = 0; sub < 16; ++sub) {
    const float* rp = ab + (size_t)(row0 + sub * 4) * 768 + cbase;
    float4 vv[4][3];
#pragma unroll
    for (int s = 0; s < 4; ++s)
#pragma unroll
      for (int j = 0; j < 3; ++j)
        vv[s][j] = *(const float4*)(rp + s * 768 + 4 * j);

    float q[3][4];
#pragma unroll
    for (int t3 = 0; t3 < 3; ++t3)
#pragma unroll
      for (int s = 0; s < 4; ++s) {
        float d = 0.f;
#pragma unroll
        for (int j = 0; j < 3; ++j) {
          d = fmaf(vv[s][j].x, hh[t3][j].x, d);
          d = fmaf(vv[s][j].y, hh[t3][j].y, d);
          d = fmaf(vv[s][j].z, hh[t3][j].z, d);
          d = fmaf(vv[s][j].w, hh[t3][j].w, d);
        }
        q[t3][s] = d;
      }
#pragma unroll
    for (int t3 = 0; t3 < 3; ++t3)
#pragma unroll
      for (int s = 0; s < 4; ++s) {
#pragma unroll
        for (int d = 1; d < 64; d <<= 1)
          q[t3][s] += __shfl_xor(q[t3][s], d);
        q[t3][s] = __expf(q[t3][s]);
      }
#pragma unroll
    for (int t3 = 0; t3 < 3; ++t3)
#pragma unroll
      for (int s = 0; s < 4; ++s) {
        const float p = q[t3][s];
        lsum[t3] += p;
#pragma unroll
        for (int j = 0; j < 3; ++j) {
          acc[t3][j].x = fmaf(p, vv[s][j].x, acc[t3][j].x);
          acc[t3][j].y = fmaf(p, vv[s][j].y, acc[t3][j].y);
          acc[t3][j].z = fmaf(p, vv[s][j].z, acc[t3][j].z);
          acc[t3][j].w = fmaf(p, vv[s][j].w, acc[t3][j].w);
        }
      }
  }

#pragma unroll
  for (int t3 = 0; t3 < 3; ++t3)
#pragma unroll
    for (int j = 0; j < 3; ++j)
      *(float4*)(&accW[wv][t3][cbase + 4 * j]) = acc[t3][j];
  if (lane == 0) {
#pragma unroll
    for (int t3 = 0; t3 < 3; ++t3) lsumW[wv][t3] = lsum[t3];
  }
  __syncthreads();

  float ltot[3];
#pragma unroll
  for (int t3 = 0; t3 < 3; ++t3)
    ltot[t3] = lsumW[0][t3] + lsumW[1][t3] + lsumW[2][t3] + lsumW[3][t3];
  u16* outs[3] = { a1, a2, a3 };
#pragma unroll
  for (int cc = 0; cc < 3; ++cc) {
    const int c = tid + cc * 256;
#pragma unroll
    for (int t3 = 0; t3 < 3; ++t3) {
      float s = accW[0][t3][c] + accW[1][t3][c] + accW[2][t3][c] + accW[3][t3][c];
      outs[t3][b * 768 + c] = f2h(s / ltot[t3]);
    }
  }
}

// ---------------------------------------------------------------------------
extern "C" void kernel_launch(void* const* d_in, const int* in_sizes, int n_in,
                              void* d_out, int out_size, void* d_ws, size_t ws_size,
                              hipStream_t stream)
{
  const float* x    = (const float*)d_in[0];
  const float* attn = (const float*)d_in[1];
  const float* Wih  = (const float*)d_in[2];
  const float* Whh  = (const float*)d_in[3];
  const float* bih  = (const float*)d_in[4];
  const float* bhh  = (const float*)d_in[5];
  const float* hfcW = (const float*)d_in[6];
  const float* hfcb = (const float*)d_in[7];
  const float* cfcW = (const float*)d_in[8];
  const float* cfcb = (const float*)d_in[9];
  const float* midW = (const float*)d_in[10];
  const float* midb = (const float*)d_in[11];
  const float* o1W  = (const float*)d_in[12];
  const float* o1b  = (const float*)d_in[13];
  const float* o2W  = (const float*)d_in[14];
  const float* o2b  = (const float*)d_in[15];
  const float* o3W  = (const float*)d_in[16];
  const float* o3b  = (const float*)d_in[17];
  float* out = (float*)d_out;
  char*  ws  = (char*)d_ws;

  float* Gpre = (float*)(ws + 0);               // 1024 x 6144 (tasks 2,3 pre-gates)
  float* h1f  = (float*)(ws + 25165824);
  float* c1f  = (float*)(ws + 28311552);
  float* h2f  = (float*)(ws + 31457280);
  float* cp3f = (float*)(ws + 34603008);
  float* h3f  = (float*)(ws + 37748736);
  u16*   xh   = (u16*)(ws + 40894464);
  u16*   Wihh = (u16*)(ws + 42467328);          // all 3 tasks, 9216x768
  u16*   Whhh = (u16*)(ws + 56623104);          // Whh[1], Whh[2]
  u16*   hfch = (u16*)(ws + 66060288);
  u16*   cfch = (u16*)(ws + 67239936);
  u16*   midh = (u16*)(ws + 68419584);
  u16*   o1h  = (u16*)(ws + 71958528);
  u16*   o2h  = (u16*)(ws + 72268800);
  u16*   o3h  = (u16*)(ws + 72549888);
  u16*   h1h  = (u16*)(ws + 72566784);
  u16*   h2h  = (u16*)(ws + 74139648);
  u16*   c2h  = (u16*)(ws + 75712512);
  u16*   hp3h = (u16*)(ws + 77285376);
  u16*   a1h  = (u16*)(ws + 78858240);
  u16*   a2h  = (u16*)(ws + 80431104);
  u16*   a3h  = (u16*)(ws + 82003968);
  u16*   m1h  = (u16*)(ws + 83576832);
  u16*   m2h  = (u16*)(ws + 85149696);
  u16*   m3h  = (u16*)(ws + 86722560);
  // workspace end: 88,295,424 bytes

  // ---- 1. fp32 -> fp16 conversions ----
  CvtArgs ca;
  const float* srcs[9] = { x, Wih, Whh + 2359296, hfcW, cfcW, midW, o1W, o2W, o3W };
  u16*         dsts[9] = { xh, Wihh, Whhh, hfch, cfch, midh, o1h, o2h, o3h };
  int ns[9] = { 786432, 7077888, 4718592, 589824, 589824, 1769472, 155136, 140544, 8448 };
  int pfx = 0;
  for (int i = 0; i < 9; ++i) {
    ca.src[i] = srcs[i]; ca.dst[i] = dsts[i]; ca.n[i] = ns[i];
    ca.pfx[i] = pfx; pfx += (ns[i] + 1023) / 1024;
  }
  ca.pfx[9] = pfx;
  cvt_k<<<pfx, 256, 0, stream>>>(ca);

  GArgs P;

  // ---- 2. Gpre = x*Wih[1,2]^T + bih + bhh  (tasks 2,3; N=6144) ----
  P = GArgs{};
  P.j[0] = { xh, Wihh + (size_t)3072 * 768, Gpre, nullptr,
             bih + 3072, bhh + 3072, nullptr, 6144, 6144, 0 };
  gemm_k<<<dim3(48, 8, 1), 256, 0, stream>>>(P, 768);

  // ---- 3. cell1 (no recurrent term): gates = x*Wih1^T + bih1 + bhh1 ----
  cell_k<<<dim3(24, 8), 256, 0, stream>>>(xh, Wihh, bih, bhh,
      nullptr, 0, nullptr, h1f, c1f, h1h, nullptr, 768);

  // ---- 4. cell2: gates = Gpre[task2] + h1*Whh[1]^T ----
  cell_k<<<dim3(24, 8), 256, 0, stream>>>(h1h, Whhh, nullptr, nullptr,
      Gpre, 6144, c1f, h2f, nullptr, h2h, c2h, 768);

  // ---- 5. hp3 = h1 + h2*hfcW^T + hfcb ; cp3 = c1 + c2*cfcW^T + cfcb ----
  P = GArgs{};
  P.j[0] = { h2h, hfch, nullptr, hp3h, hfcb, nullptr, h1f, 768, 768, 0 };
  P.j[1] = { c2h, cfch, cp3f, nullptr, cfcb, nullptr, c1f, 768, 768, 0 };
  gemm_k<<<dim3(6, 8, 2), 256, 0, stream>>>(P, 768);

  // ---- 6. cell3: gates = Gpre[task3] + hp3*Whh[2]^T ----
  cell_k<<<dim3(24, 8), 256, 0, stream>>>(hp3h, Whhh + 2359296, nullptr, nullptr,
      Gpre + 3072, 6144, cp3f, h3f, nullptr, nullptr, nullptr, 768);

  // ---- 7. fused attention (single pass over attn) ----
  attn_k<<<1024, 256, 0, stream>>>(attn, h1f, h2f, h3f, a1h, a2h, a3h);

  // ---- 8. heads: m = relu(a*midW^T + midb), 3 tasks batched ----
  P = GArgs{};
  P.j[0] = { a1h, midh,           nullptr, m1h, midb,        nullptr, nullptr, 768, 768, 1 };
  P.j[1] = { a2h, midh +  589824, nullptr, m2h, midb +  768, nullptr, nullptr, 768, 768, 1 };
  P.j[2] = { a3h, midh + 1179648, nullptr, m3h, midb + 1536, nullptr, nullptr, 768, 768, 1 };
  gemm_k<<<dim3(6, 8, 3), 256, 0, stream>>>(P, 768);

  // ---- 9. output heads, 3 tasks batched ----
  P = GArgs{};
  P.j[0] = { m1h, o1h, out,          nullptr, o1b, nullptr, nullptr, 202, 202, 0 };
  P.j[1] = { m2h, o2h, out + 206848, nullptr, o2b, nullptr, nullptr, 183, 183, 0 };
  P.j[2] = { m3h, o3h, out + 394240, nullptr, o3b, nullptr, nullptr,  11,  11, 0 };
  gemm_k<<<dim3(2, 8, 3), 256, 0, stream>>>(P, 768);

  (void)in_sizes; (void)n_in; (void)out_size; (void)ws_size;
}

// Round 4
// 348.949 us; speedup vs baseline: 2.1612x; 1.1278x over previous
//
#include <hip/hip_runtime.h>

// ---------------------------------------------------------------------------
// LSTMDecoder: 3 chained LSTM cells + edge FC + 3-head attention + heads.
// B=1024, H=768, S=256, C=(202,183,11).
// R4: BM=64 tiles (2x grid, ~3 blocks/CU for latency hiding) + 2-phase
// double-buffered global_load_lds prefetch (stage t+1 before compute t,
// ONE __syncthreads per iter). Attention: coalesced lane-owns
// {256j+4*lane} columns (contiguous 1KB per load instr), wave-local dots.
// fp16 MFMA everywhere; fused LSTM-cell epilogues (gate-stripe layout).
// ---------------------------------------------------------------------------

typedef unsigned short u16;
typedef _Float16       f16x8 __attribute__((ext_vector_type(8)));
typedef float          f32x4 __attribute__((ext_vector_type(4)));

#define SWZ(r) ((((r) + ((r) >> 2))) & 3)

__device__ __forceinline__ u16 f2h(float f) {
  _Float16 h = (_Float16)f;
  return __builtin_bit_cast(u16, h);
}
__device__ __forceinline__ float sigm(float x) { return 1.f / (1.f + __expf(-x)); }
__device__ __forceinline__ float ftanh(float x) { return 1.f - 2.f / (__expf(2.f * x) + 1.f); }

__device__ __forceinline__ void gld16(const u16* g, u16* l) {
  __builtin_amdgcn_global_load_lds(
      (const __attribute__((address_space(1))) unsigned int*)(g),
      (__attribute__((address_space(3))) unsigned int*)(l),
      16, 0, 0);
}

// ---------------------------------------------------------------------------
// Plain GEMM: out[1024][N] = A[1024xK]*W[NxK]^T (+bias)(+bias2)(+addend)(relu)
// 64x128 tile, BK=32, 4 waves: wave w owns rows [w*16,w*16+16) x 128 cols
// (acc[8]). Double-buffered LDS, prefetch-next-then-compute, 1 barrier/iter.
// ---------------------------------------------------------------------------
struct GJob {
  const u16* A; const u16* W;
  float* outf; u16* outh;
  const float* bias; const float* bias2; const float* addend;
  int N; int ldc; int relu;
};
struct GArgs { GJob j[3]; };

__global__ __launch_bounds__(256)
void gemm_k(GArgs P, int K)
{
  const GJob jb = P.j[blockIdx.z];
  const int bn0 = blockIdx.x * 128;
  if (bn0 >= jb.N) return;
  const int bm0 = blockIdx.y * 64;

  __shared__ __align__(16) u16 As[2][64 * 32];
  __shared__ __align__(16) u16 Bs[2][128 * 32];

  const int tid = threadIdx.x, lane = tid & 63, wv = tid >> 6;

  // staging: A = 256 chunks (1/thread), B = 512 chunks (2/thread); chunk q:
  // row r=q>>2, phys slot p=q&3 holds logical slot p^SWZ(r) (pre-swizzled src)
  const int ra  = tid >> 2,        csa  = (tid & 3) ^ SWZ(ra);
  const int rb0 = tid >> 2,        csb0 = (tid & 3) ^ SWZ(rb0);
  const int rb1 = (tid >> 2) + 64, csb1 = (tid & 3) ^ SWZ(rb1);
  int wr0 = bn0 + rb0; if (wr0 >= jb.N) wr0 = jb.N - 1;
  int wr1 = bn0 + rb1; if (wr1 >= jb.N) wr1 = jb.N - 1;
  const u16* gA  = jb.A + (size_t)(bm0 + ra) * K + csa * 8;
  const u16* gB0 = jb.W + (size_t)wr0 * K + csb0 * 8;
  const u16* gB1 = jb.W + (size_t)wr1 * K + csb1 * 8;

  const int frow = lane & 15, fsl = lane >> 4;

  f32x4 acc[8];
#pragma unroll
  for (int n = 0; n < 8; ++n) acc[n] = (f32x4){0.f, 0.f, 0.f, 0.f};

  const int NT = K >> 5;
  gld16(gA,  &As[0][wv * 512]);
  gld16(gB0, &Bs[0][wv * 512]);
  gld16(gB1, &Bs[0][2048 + wv * 512]);
  __syncthreads();

  for (int it = 0; it < NT; ++it) {
    const int cur = it & 1, nxt = cur ^ 1;
    if (it + 1 < NT) {
      const int k0 = (it + 1) * 32;
      gld16(gA + k0,  &As[nxt][wv * 512]);
      gld16(gB0 + k0, &Bs[nxt][wv * 512]);
      gld16(gB1 + k0, &Bs[nxt][2048 + wv * 512]);
    }
    f16x8 ah, bh[8];
    {
      const int ar = wv * 16 + frow;
      ah = *(const f16x8*)(&As[cur][ar * 32 + ((fsl ^ SWZ(ar)) * 8)]);
    }
#pragma unroll
    for (int n = 0; n < 8; ++n) {
      const int br = n * 16 + frow;
      bh[n] = *(const f16x8*)(&Bs[cur][br * 32 + ((fsl ^ SWZ(br)) * 8)]);
    }
#pragma unroll
    for (int n = 0; n < 8; ++n)
      acc[n] = __builtin_amdgcn_mfma_f32_16x16x32_f16(ah, bh[n], acc[n], 0, 0, 0);
    __syncthreads();   // drains prefetch (vmcnt0+lgkm0) + barrier: tile t+1 ready
  }

  // epilogue: C/D layout col=lane&15, row=(lane>>4)*4+reg  [m89-verified]
  const int rb = (lane >> 4) * 4;
  const int cc = lane & 15;
#pragma unroll
  for (int n = 0; n < 8; ++n) {
    const int col = bn0 + n * 16 + cc;
    if (col >= jb.N) continue;
    float bv = 0.f;
    if (jb.bias)  bv += jb.bias[col];
    if (jb.bias2) bv += jb.bias2[col];
    const int row0 = bm0 + wv * 16 + rb;
#pragma unroll
    for (int r = 0; r < 4; ++r) {
      const int row = row0 + r;
      float v = acc[n][r] + bv;
      if (jb.addend) v += jb.addend[(size_t)row * jb.ldc + col];
      if (jb.relu)   v = fmaxf(v, 0.f);
      if (jb.outf)   jb.outf[(size_t)row * jb.ldc + col] = v;
      if (jb.outh)   jb.outh[(size_t)row * jb.ldc + col] = f2h(v);
    }
  }
}

// ---------------------------------------------------------------------------
// Fused LSTM-cell GEMM: gates = A*W^T (+bih+bhh | +addend), cell math in
// epilogue. Tile = 64 rows x 32 j-cols x 4 gates (B-tile 128 rows);
// B row r_lds <-> W row (r_lds>>5)*768 + bj0 + (r_lds&31). Wave w owns
// rows [w*16,w*16+16) x all 128 B-rows -> thread holds i,f,g,o per (row,j).
// ---------------------------------------------------------------------------
__global__ __launch_bounds__(256)
void cell_k(const u16* __restrict__ A, const u16* __restrict__ W,
            const float* __restrict__ bi, const float* __restrict__ bh_,
            const float* __restrict__ addend, int lda,
            const float* __restrict__ cprev,
            float* __restrict__ hf, float* __restrict__ cf,
            u16* __restrict__ hh, u16* __restrict__ ch, int K)
{
  const int bj0 = blockIdx.x * 32;
  const int bm0 = blockIdx.y * 64;

  __shared__ __align__(16) u16 As[2][64 * 32];
  __shared__ __align__(16) u16 Bs[2][128 * 32];

  const int tid = threadIdx.x, lane = tid & 63, wv = tid >> 6;

  const int ra  = tid >> 2,        csa  = (tid & 3) ^ SWZ(ra);
  const int rb0 = tid >> 2,        csb0 = (tid & 3) ^ SWZ(rb0);
  const int rb1 = (tid >> 2) + 64, csb1 = (tid & 3) ^ SWZ(rb1);
  const int wr0 = (rb0 >> 5) * 768 + bj0 + (rb0 & 31);
  const int wr1 = (rb1 >> 5) * 768 + bj0 + (rb1 & 31);
  const u16* gA  = A + (size_t)(bm0 + ra) * K + csa * 8;
  const u16* gB0 = W + (size_t)wr0 * K + csb0 * 8;
  const u16* gB1 = W + (size_t)wr1 * K + csb1 * 8;

  const int frow = lane & 15, fsl = lane >> 4;

  f32x4 acc[8];
#pragma unroll
  for (int n = 0; n < 8; ++n) acc[n] = (f32x4){0.f, 0.f, 0.f, 0.f};

  const int NT = K >> 5;
  gld16(gA,  &As[0][wv * 512]);
  gld16(gB0, &Bs[0][wv * 512]);
  gld16(gB1, &Bs[0][2048 + wv * 512]);
  __syncthreads();

  for (int it = 0; it < NT; ++it) {
    const int cur = it & 1, nxt = cur ^ 1;
    if (it + 1 < NT) {
      const int k0 = (it + 1) * 32;
      gld16(gA + k0,  &As[nxt][wv * 512]);
      gld16(gB0 + k0, &Bs[nxt][wv * 512]);
      gld16(gB1 + k0, &Bs[nxt][2048 + wv * 512]);
    }
    f16x8 ah, bh8[8];
    {
      const int ar = wv * 16 + frow;
      ah = *(const f16x8*)(&As[cur][ar * 32 + ((fsl ^ SWZ(ar)) * 8)]);
    }
#pragma unroll
    for (int n = 0; n < 8; ++n) {
      const int br = n * 16 + frow;
      bh8[n] = *(const f16x8*)(&Bs[cur][br * 32 + ((fsl ^ SWZ(br)) * 8)]);
    }
#pragma unroll
    for (int n = 0; n < 8; ++n)
      acc[n] = __builtin_amdgcn_mfma_f32_16x16x32_f16(ah, bh8[n], acc[n], 0, 0, 0);
    __syncthreads();
  }

  // epilogue: n = gate*2 + jj  -> full i,f,g,o per (row, j)
  const int rb = (lane >> 4) * 4;
  const int cc = lane & 15;
#pragma unroll
  for (int jj = 0; jj < 2; ++jj) {
    const int j = bj0 + jj * 16 + cc;
    float b_i = 0.f, b_f = 0.f, b_g = 0.f, b_o = 0.f;
    if (bi) {
      b_i = bi[j]        + bh_[j];
      b_f = bi[768 + j]  + bh_[768 + j];
      b_g = bi[1536 + j] + bh_[1536 + j];
      b_o = bi[2304 + j] + bh_[2304 + j];
    }
    const int row0 = bm0 + wv * 16 + rb;
#pragma unroll
    for (int r = 0; r < 4; ++r) {
      const int row = row0 + r;
      float gi = acc[0 + jj][r] + b_i;
      float gf = acc[2 + jj][r] + b_f;
      float gg = acc[4 + jj][r] + b_g;
      float go = acc[6 + jj][r] + b_o;
      if (addend) {
        const float* ad = addend + (size_t)row * lda;
        gi += ad[j]; gf += ad[768 + j]; gg += ad[1536 + j]; go += ad[2304 + j];
      }
      float c = sigm(gi) * ftanh(gg);
      if (cprev) c += sigm(gf) * cprev[row * 768 + j];
      float h = sigm(go) * ftanh(c);
      if (hf) hf[row * 768 + j] = h;
      if (cf) cf[row * 768 + j] = c;
      if (hh) hh[row * 768 + j] = f2h(h);
      if (ch) ch[row * 768 + j] = f2h(c);
    }
  }
}

// ---------------------------------------------------------------------------
// fp32 -> fp16 converter, multi-segment in one launch
// ---------------------------------------------------------------------------
struct CvtArgs {
  const float* src[9];
  u16*         dst[9];
  int n[9];
  int pfx[10];
};

__global__ __launch_bounds__(256)
void cvt_k(CvtArgs a)
{
  int blk = blockIdx.x, s = 0;
  while (s < 8 && blk >= a.pfx[s + 1]) ++s;
  int idx = ((blk - a.pfx[s]) * 256 + (int)threadIdx.x) * 4;
  if (idx >= a.n[s]) return;
  float4 v = *(const float4*)(a.src[s] + idx);
  ushort4 h;
  h.x = f2h(v.x); h.y = f2h(v.y); h.z = f2h(v.z); h.w = f2h(v.w);
  *(ushort4*)(a.dst[s] + idx) = h;
}

// ---------------------------------------------------------------------------
// Fused attention, all 3 tasks, single pass over attn (805 MB fp32).
// Block = 4 waves; wave w owns rows [w*64,w*64+64). Lane owns columns
// {256*j + 4*lane + r} (j=0..2, r=0..3): every float4 load instruction is
// 64 lanes x 16B CONTIGUOUS (1 KB). Dots wave-local via shfl butterfly;
// unnormalized exp; one end-of-kernel LDS combine.
// ---------------------------------------------------------------------------
__global__ __launch_bounds__(256)
void attn_k(const float* __restrict__ attn,
            const float* __restrict__ h1, const float* __restrict__ h2,
            const float* __restrict__ h3,
            u16* __restrict__ a1, u16* __restrict__ a2, u16* __restrict__ a3)
{
  const int b = blockIdx.x, tid = threadIdx.x;
  const int lane = tid & 63, wv = tid >> 6;
  __shared__ float accW[4][3][768];
  __shared__ float lsumW[4][3];

  const float* ab = attn + (size_t)b * 256 * 768;
  const int cb = lane * 4;

  float4 hh[3][3];
#pragma unroll
  for (int j = 0; j < 3; ++j) {
    hh[0][j] = *(const float4*)(h1 + b * 768 + j * 256 + cb);
    hh[1][j] = *(const float4*)(h2 + b * 768 + j * 256 + cb);
    hh[2][j] = *(const float4*)(h3 + b * 768 + j * 256 + cb);
  }

  float4 acc[3][3];
#pragma unroll
  for (int t3 = 0; t3 < 3; ++t3)
#pragma unroll
    for (int j = 0; j < 3; ++j) acc[t3][j] = (float4){0.f, 0.f, 0.f, 0.f};
  float lsum[3] = {0.f, 0.f, 0.f};

  const int row0 = wv * 64;
  for (int sub = 0; sub < 16; ++sub) {
    const float* rp = ab + (size_t)(row0 + sub * 4) * 768 + cb;
    float4 vv[4][3];
#pragma unroll
    for (int s = 0; s < 4; ++s)
#pragma unroll
      for (int j = 0; j < 3; ++j)
        vv[s][j] = *(const float4*)(rp + s * 768 + j * 256);

    float q[3][4];
#pragma unroll
    for (int t3 = 0; t3 < 3; ++t3)
#pragma unroll
      for (int s = 0; s < 4; ++s) {
        float d = 0.f;
#pragma unroll
        for (int j = 0; j < 3; ++j) {
          d = fmaf(vv[s][j].x, hh[t3][j].x, d);
          d = fmaf(vv[s][j].y, hh[t3][j].y, d);
          d = fmaf(vv[s][j].z, hh[t3][j].z, d);
          d = fmaf(vv[s][j].w, hh[t3][j].w, d);
        }
        q[t3][s] = d;
      }
#pragma unroll
    for (int t3 = 0; t3 < 3; ++t3)
#pragma unroll
      for (int s = 0; s < 4; ++s) {
#pragma unroll
        for (int d = 1; d < 64; d <<= 1)
          q[t3][s] += __shfl_xor(q[t3][s], d);
        q[t3][s] = __expf(q[t3][s]);
      }
#pragma unroll
    for (int t3 = 0; t3 < 3; ++t3)
#pragma unroll
      for (int s = 0; s < 4; ++s) {
        const float p = q[t3][s];
        lsum[t3] += p;
#pragma unroll
        for (int j = 0; j < 3; ++j) {
          acc[t3][j].x = fmaf(p, vv[s][j].x, acc[t3][j].x);
          acc[t3][j].y = fmaf(p, vv[s][j].y, acc[t3][j].y);
          acc[t3][j].z = fmaf(p, vv[s][j].z, acc[t3][j].z);
          acc[t3][j].w = fmaf(p, vv[s][j].w, acc[t3][j].w);
        }
      }
  }

#pragma unroll
  for (int t3 = 0; t3 < 3; ++t3)
#pragma unroll
    for (int j = 0; j < 3; ++j)
      *(float4*)(&accW[wv][t3][j * 256 + cb]) = acc[t3][j];
  if (lane == 0) {
#pragma unroll
    for (int t3 = 0; t3 < 3; ++t3) lsumW[wv][t3] = lsum[t3];
  }
  __syncthreads();

  float ltot[3];
#pragma unroll
  for (int t3 = 0; t3 < 3; ++t3)
    ltot[t3] = lsumW[0][t3] + lsumW[1][t3] + lsumW[2][t3] + lsumW[3][t3];
  u16* outs[3] = { a1, a2, a3 };
#pragma unroll
  for (int cc = 0; cc < 3; ++cc) {
    const int c = tid + cc * 256;
#pragma unroll
    for (int t3 = 0; t3 < 3; ++t3) {
      float s = accW[0][t3][c] + accW[1][t3][c] + accW[2][t3][c] + accW[3][t3][c];
      outs[t3][b * 768 + c] = f2h(s / ltot[t3]);
    }
  }
}

// ---------------------------------------------------------------------------
extern "C" void kernel_launch(void* const* d_in, const int* in_sizes, int n_in,
                              void* d_out, int out_size, void* d_ws, size_t ws_size,
                              hipStream_t stream)
{
  const float* x    = (const float*)d_in[0];
  const float* attn = (const float*)d_in[1];
  const float* Wih  = (const float*)d_in[2];
  const float* Whh  = (const float*)d_in[3];
  const float* bih  = (const float*)d_in[4];
  const float* bhh  = (const float*)d_in[5];
  const float* hfcW = (const float*)d_in[6];
  const float* hfcb = (const float*)d_in[7];
  const float* cfcW = (const float*)d_in[8];
  const float* cfcb = (const float*)d_in[9];
  const float* midW = (const float*)d_in[10];
  const float* midb = (const float*)d_in[11];
  const float* o1W  = (const float*)d_in[12];
  const float* o1b  = (const float*)d_in[13];
  const float* o2W  = (const float*)d_in[14];
  const float* o2b  = (const float*)d_in[15];
  const float* o3W  = (const float*)d_in[16];
  const float* o3b  = (const float*)d_in[17];
  float* out = (float*)d_out;
  char*  ws  = (char*)d_ws;

  float* Gpre = (float*)(ws + 0);               // 1024 x 6144 (tasks 2,3 pre-gates)
  float* h1f  = (float*)(ws + 25165824);
  float* c1f  = (float*)(ws + 28311552);
  float* h2f  = (float*)(ws + 31457280);
  float* cp3f = (float*)(ws + 34603008);
  float* h3f  = (float*)(ws + 37748736);
  u16*   xh   = (u16*)(ws + 40894464);
  u16*   Wihh = (u16*)(ws + 42467328);          // all 3 tasks, 9216x768
  u16*   Whhh = (u16*)(ws + 56623104);          // Whh[1], Whh[2]
  u16*   hfch = (u16*)(ws + 66060288);
  u16*   cfch = (u16*)(ws + 67239936);
  u16*   midh = (u16*)(ws + 68419584);
  u16*   o1h  = (u16*)(ws + 71958528);
  u16*   o2h  = (u16*)(ws + 72268800);
  u16*   o3h  = (u16*)(ws + 72549888);
  u16*   h1h  = (u16*)(ws + 72566784);
  u16*   h2h  = (u16*)(ws + 74139648);
  u16*   c2h  = (u16*)(ws + 75712512);
  u16*   hp3h = (u16*)(ws + 77285376);
  u16*   a1h  = (u16*)(ws + 78858240);
  u16*   a2h  = (u16*)(ws + 80431104);
  u16*   a3h  = (u16*)(ws + 82003968);
  u16*   m1h  = (u16*)(ws + 83576832);
  u16*   m2h  = (u16*)(ws + 85149696);
  u16*   m3h  = (u16*)(ws + 86722560);
  // workspace end: 88,295,424 bytes

  // ---- 1. fp32 -> fp16 conversions ----
  CvtArgs ca;
  const float* srcs[9] = { x, Wih, Whh + 2359296, hfcW, cfcW, midW, o1W, o2W, o3W };
  u16*         dsts[9] = { xh, Wihh, Whhh, hfch, cfch, midh, o1h, o2h, o3h };
  int ns[9] = { 786432, 7077888, 4718592, 589824, 589824, 1769472, 155136, 140544, 8448 };
  int pfx = 0;
  for (int i = 0; i < 9; ++i) {
    ca.src[i] = srcs[i]; ca.dst[i] = dsts[i]; ca.n[i] = ns[i];
    ca.pfx[i] = pfx; pfx += (ns[i] + 1023) / 1024;
  }
  ca.pfx[9] = pfx;
  cvt_k<<<pfx, 256, 0, stream>>>(ca);

  GArgs P;

  // ---- 2. Gpre = x*Wih[1,2]^T + bih + bhh  (tasks 2,3; N=6144) ----
  P = GArgs{};
  P.j[0] = { xh, Wihh + (size_t)3072 * 768, Gpre, nullptr,
             bih + 3072, bhh + 3072, nullptr, 6144, 6144, 0 };
  gemm_k<<<dim3(48, 16, 1), 256, 0, stream>>>(P, 768);

  // ---- 3. cell1 (no recurrent term): gates = x*Wih1^T + bih1 + bhh1 ----
  cell_k<<<dim3(24, 16), 256, 0, stream>>>(xh, Wihh, bih, bhh,
      nullptr, 0, nullptr, h1f, c1f, h1h, nullptr, 768);

  // ---- 4. cell2: gates = Gpre[task2] + h1*Whh[1]^T ----
  cell_k<<<dim3(24, 16), 256, 0, stream>>>(h1h, Whhh, nullptr, nullptr,
      Gpre, 6144, c1f, h2f, nullptr, h2h, c2h, 768);

  // ---- 5. hp3 = h1 + h2*hfcW^T + hfcb ; cp3 = c1 + c2*cfcW^T + cfcb ----
  P = GArgs{};
  P.j[0] = { h2h, hfch, nullptr, hp3h, hfcb, nullptr, h1f, 768, 768, 0 };
  P.j[1] = { c2h, cfch, cp3f, nullptr, cfcb, nullptr, c1f, 768, 768, 0 };
  gemm_k<<<dim3(6, 16, 2), 256, 0, stream>>>(P, 768);

  // ---- 6. cell3: gates = Gpre[task3] + hp3*Whh[2]^T ----
  cell_k<<<dim3(24, 16), 256, 0, stream>>>(hp3h, Whhh + 2359296, nullptr, nullptr,
      Gpre + 3072, 6144, cp3f, h3f, nullptr, nullptr, nullptr, 768);

  // ---- 7. fused attention (single pass over attn) ----
  attn_k<<<1024, 256, 0, stream>>>(attn, h1f, h2f, h3f, a1h, a2h, a3h);

  // ---- 8. heads: m = relu(a*midW^T + midb), 3 tasks batched ----
  P = GArgs{};
  P.j[0] = { a1h, midh,           nullptr, m1h, midb,        nullptr, nullptr, 768, 768, 1 };
  P.j[1] = { a2h, midh +  589824, nullptr, m2h, midb +  768, nullptr, nullptr, 768, 768, 1 };
  P.j[2] = { a3h, midh + 1179648, nullptr, m3h, midb + 1536, nullptr, nullptr, 768, 768, 1 };
  gemm_k<<<dim3(6, 16, 3), 256, 0, stream>>>(P, 768);

  // ---- 9. output heads, 3 tasks batched ----
  P = GArgs{};
  P.j[0] = { m1h, o1h, out,          nullptr, o1b, nullptr, nullptr, 202, 202, 0 };
  P.j[1] = { m2h, o2h, out + 206848, nullptr, o2b, nullptr, nullptr, 183, 183, 0 };
  P.j[2] = { m3h, o3h, out + 394240, nullptr, o3b, nullptr, nullptr,  11,  11, 0 };
  gemm_k<<<dim3(2, 16, 3), 256, 0, stream>>>(P, 768);

  (void)in_sizes; (void)n_in; (void)out_size; (void)ws_size;
}

// Round 5
// 323.066 us; speedup vs baseline: 2.3344x; 1.0801x over previous
//
#include <hip/hip_runtime.h>

// ---------------------------------------------------------------------------
// LSTMDecoder: 3 chained LSTM cells + edge FC + 3-head attention + heads.
// B=1024, H=768, S=256, C=(202,183,11).
// R5: counted-vmcnt depth-2 pipeline (T4): 4 LDS buffers, stage t+3 after
// compute t, asm vmcnt(6)/raw barrier (never vmcnt(0) in main loop).
// Gpre eliminated: cell2/cell3 are K=1536 concat GEMMs (A=[x|h], W=[Wih|Whh]).
// fp16 MFMA; fused LSTM-cell epilogues; coalesced fused fp32 attention.
// ---------------------------------------------------------------------------

typedef unsigned short u16;
typedef _Float16       f16x8 __attribute__((ext_vector_type(8)));
typedef float          f32x4 __attribute__((ext_vector_type(4)));

#define SWZ(r) ((((r) + ((r) >> 2))) & 3)
#define VMCNT(N) asm volatile("s_waitcnt vmcnt(" #N ")" ::: "memory")
#define KBAR()  do { __builtin_amdgcn_s_barrier(); __builtin_amdgcn_sched_barrier(0); } while (0)

__device__ __forceinline__ u16 f2h(float f) {
  _Float16 h = (_Float16)f;
  return __builtin_bit_cast(u16, h);
}
__device__ __forceinline__ float sigm(float x) { return 1.f / (1.f + __expf(-x)); }
__device__ __forceinline__ float ftanh(float x) { return 1.f - 2.f / (__expf(2.f * x) + 1.f); }

__device__ __forceinline__ void gld16(const u16* g, u16* l) {
  __builtin_amdgcn_global_load_lds(
      (const __attribute__((address_space(1))) unsigned int*)(g),
      (__attribute__((address_space(3))) unsigned int*)(l),
      16, 0, 0);
}

// per-thread staging pointers (two K-segments; seg2 used when kt >= ntA)
struct KP { const u16 *pA1, *pA2, *pW1_0, *pW2_0, *pW1_1, *pW2_1; };

__device__ __forceinline__ void stage_tile(const KP& kp, int kt, int ntA,
                                           u16* Asb, u16* Bsb, int wv) {
  const bool s1 = (kt < ntA);
  const int off = (s1 ? kt : kt - ntA) * 32;
  gld16((s1 ? kp.pA1  : kp.pA2 ) + off, Asb + wv * 512);
  gld16((s1 ? kp.pW1_0 : kp.pW2_0) + off, Bsb + wv * 512);
  gld16((s1 ? kp.pW1_1 : kp.pW2_1) + off, Bsb + 2048 + wv * 512);
}

__device__ __forceinline__ void compute_tile(const u16* Asb, const u16* Bsb,
                                             int wv, int frow, int fsl, f32x4* acc) {
  const int ar = wv * 16 + frow;
  f16x8 ah = *(const f16x8*)(Asb + ar * 32 + ((fsl ^ SWZ(ar)) * 8));
  f16x8 bh[8];
#pragma unroll
  for (int n = 0; n < 8; ++n) {
    const int br = n * 16 + frow;
    bh[n] = *(const f16x8*)(Bsb + br * 32 + ((fsl ^ SWZ(br)) * 8));
  }
#pragma unroll
  for (int n = 0; n < 8; ++n)
    acc[n] = __builtin_amdgcn_mfma_f32_16x16x32_f16(ah, bh[n], acc[n], 0, 0, 0);
}

// depth-2 counted-vmcnt pipeline over NT k-tiles (NT >= 3)
#define KLOOP(kp, ntA, NT, As, Bs, wv, frow, fsl, acc)                          \
  do {                                                                          \
    stage_tile(kp, 0, ntA, As, Bs, wv);                                         \
    stage_tile(kp, 1, ntA, As + 2048, Bs + 4096, wv);                           \
    stage_tile(kp, 2, ntA, As + 4096, Bs + 8192, wv);                           \
    for (int t = 0; t < NT - 2; ++t) {                                          \
      VMCNT(6); KBAR();                                                         \
      const int cb = t & 3;                                                     \
      compute_tile(As + cb * 2048, Bs + cb * 4096, wv, frow, fsl, acc);         \
      if (t + 3 < NT) {                                                         \
        const int sb = (t + 3) & 3;                                             \
        stage_tile(kp, t + 3, ntA, As + sb * 2048, Bs + sb * 4096, wv);         \
      }                                                                         \
    }                                                                           \
    VMCNT(3); KBAR();                                                           \
    compute_tile(As + ((NT - 2) & 3) * 2048, Bs + ((NT - 2) & 3) * 4096,        \
                 wv, frow, fsl, acc);                                           \
    VMCNT(0); KBAR();                                                           \
    compute_tile(As + ((NT - 1) & 3) * 2048, Bs + ((NT - 1) & 3) * 4096,        \
                 wv, frow, fsl, acc);                                           \
  } while (0)

// ---------------------------------------------------------------------------
// Plain GEMM: out[1024][N] = A[1024x768]*W[Nx768]^T (+bias)(+bias2)(+addend)
// (relu). 64x128 tile, 4 waves (wave w = rows [16w,16w+16) x 128 cols).
// ---------------------------------------------------------------------------
struct GJob {
  const u16* A; const u16* W;
  float* outf; u16* outh;
  const float* bias; const float* bias2; const float* addend;
  int N; int ldc; int relu;
};
struct GArgs { GJob j[3]; };

__global__ __launch_bounds__(256)
void gemm_k(GArgs P)
{
  const GJob jb = P.j[blockIdx.z];
  const int bn0 = blockIdx.x * 128;
  if (bn0 >= jb.N) return;
  const int bm0 = blockIdx.y * 64;

  __shared__ __align__(16) u16 As[4 * 64 * 32];    // 16 KB
  __shared__ __align__(16) u16 Bs[4 * 128 * 32];   // 32 KB

  const int tid = threadIdx.x, lane = tid & 63, wv = tid >> 6;
  const int frow = lane & 15, fsl = lane >> 4;

  const int ra  = tid >> 2,        csa  = (tid & 3) ^ SWZ(ra);
  const int rb0 = tid >> 2,        csb0 = (tid & 3) ^ SWZ(rb0);
  const int rb1 = (tid >> 2) + 64, csb1 = (tid & 3) ^ SWZ(rb1);
  int wr0 = bn0 + rb0; if (wr0 >= jb.N) wr0 = jb.N - 1;
  int wr1 = bn0 + rb1; if (wr1 >= jb.N) wr1 = jb.N - 1;

  KP kp;
  kp.pA1 = kp.pA2 = jb.A + (size_t)(bm0 + ra) * 768 + csa * 8;
  kp.pW1_0 = kp.pW2_0 = jb.W + (size_t)wr0 * 768 + csb0 * 8;
  kp.pW1_1 = kp.pW2_1 = jb.W + (size_t)wr1 * 768 + csb1 * 8;

  f32x4 acc[8];
#pragma unroll
  for (int n = 0; n < 8; ++n) acc[n] = (f32x4){0.f, 0.f, 0.f, 0.f};

  KLOOP(kp, 24, 24, As, Bs, wv, frow, fsl, acc);

  // epilogue: C/D layout col=lane&15, row=(lane>>4)*4+reg  [m89-verified]
  const int rb = (lane >> 4) * 4;
  const int cc = lane & 15;
#pragma unroll
  for (int n = 0; n < 8; ++n) {
    const int col = bn0 + n * 16 + cc;
    if (col >= jb.N) continue;
    float bv = 0.f;
    if (jb.bias)  bv += jb.bias[col];
    if (jb.bias2) bv += jb.bias2[col];
    const int row0 = bm0 + wv * 16 + rb;
#pragma unroll
    for (int r = 0; r < 4; ++r) {
      const int row = row0 + r;
      float v = acc[n][r] + bv;
      if (jb.addend) v += jb.addend[(size_t)row * jb.ldc + col];
      if (jb.relu)   v = fmaxf(v, 0.f);
      if (jb.outf)   jb.outf[(size_t)row * jb.ldc + col] = v;
      if (jb.outh)   jb.outh[(size_t)row * jb.ldc + col] = f2h(v);
    }
  }
}

// ---------------------------------------------------------------------------
// Fused LSTM-cell GEMM, concat-K: gates = [A1|A2] * [W1|W2]^T + bi + bh_,
// then cell math in epilogue. Tile = 64 rows x 32 j-cols x 4 gates
// (B-tile row r <-> W row (r>>5)*768 + bj0 + (r&31)). K = ntA*32 (+768 if
// A2 segment present). Wave w = rows [16w,16w+16); thread owns i,f,g,o.
// ---------------------------------------------------------------------------
__global__ __launch_bounds__(256)
void cell_k(const u16* __restrict__ A1, const u16* __restrict__ A2,
            const u16* __restrict__ W1, const u16* __restrict__ W2,
            const float* __restrict__ bi, const float* __restrict__ bh_,
            const float* __restrict__ cprev,
            float* __restrict__ hf, float* __restrict__ cf,
            u16* __restrict__ hh, u16* __restrict__ ch, int NT)
{
  const int bj0 = blockIdx.x * 32;
  const int bm0 = blockIdx.y * 64;

  __shared__ __align__(16) u16 As[4 * 64 * 32];
  __shared__ __align__(16) u16 Bs[4 * 128 * 32];

  const int tid = threadIdx.x, lane = tid & 63, wv = tid >> 6;
  const int frow = lane & 15, fsl = lane >> 4;

  const int ra  = tid >> 2,        csa  = (tid & 3) ^ SWZ(ra);
  const int rb0 = tid >> 2,        csb0 = (tid & 3) ^ SWZ(rb0);
  const int rb1 = (tid >> 2) + 64, csb1 = (tid & 3) ^ SWZ(rb1);
  const int wr0 = (rb0 >> 5) * 768 + bj0 + (rb0 & 31);
  const int wr1 = (rb1 >> 5) * 768 + bj0 + (rb1 & 31);

  KP kp;
  kp.pA1  = A1 + (size_t)(bm0 + ra) * 768 + csa * 8;
  kp.pA2  = A2 + (size_t)(bm0 + ra) * 768 + csa * 8;
  kp.pW1_0 = W1 + (size_t)wr0 * 768 + csb0 * 8;
  kp.pW2_0 = W2 + (size_t)wr0 * 768 + csb0 * 8;
  kp.pW1_1 = W1 + (size_t)wr1 * 768 + csb1 * 8;
  kp.pW2_1 = W2 + (size_t)wr1 * 768 + csb1 * 8;

  f32x4 acc[8];
#pragma unroll
  for (int n = 0; n < 8; ++n) acc[n] = (f32x4){0.f, 0.f, 0.f, 0.f};

  KLOOP(kp, 24, NT, As, Bs, wv, frow, fsl, acc);

  // epilogue: n = gate*2 + jj  -> full i,f,g,o per (row, j)
  const int rb = (lane >> 4) * 4;
  const int cc = lane & 15;
#pragma unroll
  for (int jj = 0; jj < 2; ++jj) {
    const int j = bj0 + jj * 16 + cc;
    const float b_i = bi[j]        + bh_[j];
    const float b_f = bi[768 + j]  + bh_[768 + j];
    const float b_g = bi[1536 + j] + bh_[1536 + j];
    const float b_o = bi[2304 + j] + bh_[2304 + j];
    const int row0 = bm0 + wv * 16 + rb;
#pragma unroll
    for (int r = 0; r < 4; ++r) {
      const int row = row0 + r;
      float gi = acc[0 + jj][r] + b_i;
      float gf = acc[2 + jj][r] + b_f;
      float gg = acc[4 + jj][r] + b_g;
      float go = acc[6 + jj][r] + b_o;
      float c = sigm(gi) * ftanh(gg);
      if (cprev) c += sigm(gf) * cprev[row * 768 + j];
      float h = sigm(go) * ftanh(c);
      if (hf) hf[row * 768 + j] = h;
      if (cf) cf[row * 768 + j] = c;
      if (hh) hh[row * 768 + j] = f2h(h);
      if (ch) ch[row * 768 + j] = f2h(c);
    }
  }
}

// ---------------------------------------------------------------------------
// fp32 -> fp16 converter, multi-segment in one launch
// ---------------------------------------------------------------------------
struct CvtArgs {
  const float* src[9];
  u16*         dst[9];
  int n[9];
  int pfx[10];
};

__global__ __launch_bounds__(256)
void cvt_k(CvtArgs a)
{
  int blk = blockIdx.x, s = 0;
  while (s < 8 && blk >= a.pfx[s + 1]) ++s;
  int idx = ((blk - a.pfx[s]) * 256 + (int)threadIdx.x) * 4;
  if (idx >= a.n[s]) return;
  float4 v = *(const float4*)(a.src[s] + idx);
  ushort4 h;
  h.x = f2h(v.x); h.y = f2h(v.y); h.z = f2h(v.z); h.w = f2h(v.w);
  *(ushort4*)(a.dst[s] + idx) = h;
}

// ---------------------------------------------------------------------------
// Fused attention, all 3 tasks, single pass over attn (805 MB fp32).
// Block = 4 waves; wave w owns rows [w*64,w*64+64). Lane owns columns
// {256*j + 4*lane + r}: every float4 load is 64 lanes x 16B contiguous.
// Dots wave-local via shfl butterfly; unnormalized exp; one LDS combine.
// ---------------------------------------------------------------------------
__global__ __launch_bounds__(256)
void attn_k(const float* __restrict__ attn,
            const float* __restrict__ h1, const float* __restrict__ h2,
            const float* __restrict__ h3,
            u16* __restrict__ a1, u16* __restrict__ a2, u16* __restrict__ a3)
{
  const int b = blockIdx.x, tid = threadIdx.x;
  const int lane = tid & 63, wv = tid >> 6;
  __shared__ float accW[4][3][768];
  __shared__ float lsumW[4][3];

  const float* ab = attn + (size_t)b * 256 * 768;
  const int cb = lane * 4;

  float4 hh[3][3];
#pragma unroll
  for (int j = 0; j < 3; ++j) {
    hh[0][j] = *(const float4*)(h1 + b * 768 + j * 256 + cb);
    hh[1][j] = *(const float4*)(h2 + b * 768 + j * 256 + cb);
    hh[2][j] = *(const float4*)(h3 + b * 768 + j * 256 + cb);
  }

  float4 acc[3][3];
#pragma unroll
  for (int t3 = 0; t3 < 3; ++t3)
#pragma unroll
    for (int j = 0; j < 3; ++j) acc[t3][j] = (float4){0.f, 0.f, 0.f, 0.f};
  float lsum[3] = {0.f, 0.f, 0.f};

  const int row0 = wv * 64;
  for (int sub = 0; sub < 16; ++sub) {
    const float* rp = ab + (size_t)(row0 + sub * 4) * 768 + cb;
    float4 vv[4][3];
#pragma unroll
    for (int s = 0; s < 4; ++s)
#pragma unroll
      for (int j = 0; j < 3; ++j)
        vv[s][j] = *(const float4*)(rp + s * 768 + j * 256);

    float q[3][4];
#pragma unroll
    for (int t3 = 0; t3 < 3; ++t3)
#pragma unroll
      for (int s = 0; s < 4; ++s) {
        float d = 0.f;
#pragma unroll
        for (int j = 0; j < 3; ++j) {
          d = fmaf(vv[s][j].x, hh[t3][j].x, d);
          d = fmaf(vv[s][j].y, hh[t3][j].y, d);
          d = fmaf(vv[s][j].z, hh[t3][j].z, d);
          d = fmaf(vv[s][j].w, hh[t3][j].w, d);
        }
        q[t3][s] = d;
      }
#pragma unroll
    for (int t3 = 0; t3 < 3; ++t3)
#pragma unroll
      for (int s = 0; s < 4; ++s) {
#pragma unroll
        for (int d = 1; d < 64; d <<= 1)
          q[t3][s] += __shfl_xor(q[t3][s], d);
        q[t3][s] = __expf(q[t3][s]);
      }
#pragma unroll
    for (int t3 = 0; t3 < 3; ++t3)
#pragma unroll
      for (int s = 0; s < 4; ++s) {
        const float p = q[t3][s];
        lsum[t3] += p;
#pragma unroll
        for (int j = 0; j < 3; ++j) {
          acc[t3][j].x = fmaf(p, vv[s][j].x, acc[t3][j].x);
          acc[t3][j].y = fmaf(p, vv[s][j].y, acc[t3][j].y);
          acc[t3][j].z = fmaf(p, vv[s][j].z, acc[t3][j].z);
          acc[t3][j].w = fmaf(p, vv[s][j].w, acc[t3][j].w);
        }
      }
  }

#pragma unroll
  for (int t3 = 0; t3 < 3; ++t3)
#pragma unroll
    for (int j = 0; j < 3; ++j)
      *(float4*)(&accW[wv][t3][j * 256 + cb]) = acc[t3][j];
  if (lane == 0) {
#pragma unroll
    for (int t3 = 0; t3 < 3; ++t3) lsumW[wv][t3] = lsum[t3];
  }
  __syncthreads();

  float ltot[3];
#pragma unroll
  for (int t3 = 0; t3 < 3; ++t3)
    ltot[t3] = lsumW[0][t3] + lsumW[1][t3] + lsumW[2][t3] + lsumW[3][t3];
  u16* outs[3] = { a1, a2, a3 };
#pragma unroll
  for (int cc = 0; cc < 3; ++cc) {
    const int c = tid + cc * 256;
#pragma unroll
    for (int t3 = 0; t3 < 3; ++t3) {
      float s = accW[0][t3][c] + accW[1][t3][c] + accW[2][t3][c] + accW[3][t3][c];
      outs[t3][b * 768 + c] = f2h(s / ltot[t3]);
    }
  }
}

// ---------------------------------------------------------------------------
extern "C" void kernel_launch(void* const* d_in, const int* in_sizes, int n_in,
                              void* d_out, int out_size, void* d_ws, size_t ws_size,
                              hipStream_t stream)
{
  const float* x    = (const float*)d_in[0];
  const float* attn = (const float*)d_in[1];
  const float* Wih  = (const float*)d_in[2];
  const float* Whh  = (const float*)d_in[3];
  const float* bih  = (const float*)d_in[4];
  const float* bhh  = (const float*)d_in[5];
  const float* hfcW = (const float*)d_in[6];
  const float* hfcb = (const float*)d_in[7];
  const float* cfcW = (const float*)d_in[8];
  const float* cfcb = (const float*)d_in[9];
  const float* midW = (const float*)d_in[10];
  const float* midb = (const float*)d_in[11];
  const float* o1W  = (const float*)d_in[12];
  const float* o1b  = (const float*)d_in[13];
  const float* o2W  = (const float*)d_in[14];
  const float* o2b  = (const float*)d_in[15];
  const float* o3W  = (const float*)d_in[16];
  const float* o3b  = (const float*)d_in[17];
  float* out = (float*)d_out;
  char*  ws  = (char*)d_ws;

  float* h1f  = (float*)(ws + 0);
  float* c1f  = (float*)(ws + 3145728);
  float* h2f  = (float*)(ws + 6291456);
  float* cp3f = (float*)(ws + 9437184);
  float* h3f  = (float*)(ws + 12582912);
  u16*   xh   = (u16*)(ws + 15728640);
  u16*   Wihh = (u16*)(ws + 17301504);          // all 3 tasks, 9216x768
  u16*   Whhh = (u16*)(ws + 31457280);          // Whh[1], Whh[2]
  u16*   hfch = (u16*)(ws + 40894464);
  u16*   cfch = (u16*)(ws + 42074112);
  u16*   midh = (u16*)(ws + 43253760);
  u16*   o1h  = (u16*)(ws + 46792704);
  u16*   o2h  = (u16*)(ws + 47102976);
  u16*   o3h  = (u16*)(ws + 47384064);
  u16*   h1h  = (u16*)(ws + 47400960);
  u16*   h2h  = (u16*)(ws + 48973824);
  u16*   c2h  = (u16*)(ws + 50546688);
  u16*   hp3h = (u16*)(ws + 52119552);
  u16*   a1h  = (u16*)(ws + 53692416);
  u16*   a2h  = (u16*)(ws + 55265280);
  u16*   a3h  = (u16*)(ws + 56838144);
  u16*   m1h  = (u16*)(ws + 58411008);
  u16*   m2h  = (u16*)(ws + 59983872);
  u16*   m3h  = (u16*)(ws + 61556736);
  // workspace end: 63,129,600 bytes

  // ---- 1. fp32 -> fp16 conversions ----
  CvtArgs ca;
  const float* srcs[9] = { x, Wih, Whh + 2359296, hfcW, cfcW, midW, o1W, o2W, o3W };
  u16*         dsts[9] = { xh, Wihh, Whhh, hfch, cfch, midh, o1h, o2h, o3h };
  int ns[9] = { 786432, 7077888, 4718592, 589824, 589824, 1769472, 155136, 140544, 8448 };
  int pfx = 0;
  for (int i = 0; i < 9; ++i) {
    ca.src[i] = srcs[i]; ca.dst[i] = dsts[i]; ca.n[i] = ns[i];
    ca.pfx[i] = pfx; pfx += (ns[i] + 1023) / 1024;
  }
  ca.pfx[9] = pfx;
  cvt_k<<<pfx, 256, 0, stream>>>(ca);

  GArgs P;

  // ---- 2. cell1: gates = x*Wih1^T + bih1 + bhh1 (no recurrent term) ----
  cell_k<<<dim3(24, 16), 256, 0, stream>>>(xh, xh, Wihh, Wihh,
      bih, bhh, nullptr, h1f, c1f, h1h, nullptr, 24);

  // ---- 3. cell2: gates = [x|h1]*[Wih2|Whh1]^T + bih2 + bhh2 ----
  cell_k<<<dim3(24, 16), 256, 0, stream>>>(xh, h1h,
      Wihh + (size_t)3072 * 768, Whhh,
      bih + 3072, bhh + 3072, c1f, h2f, nullptr, h2h, c2h, 48);

  // ---- 4. hp3 = h1 + h2*hfcW^T + hfcb ; cp3 = c1 + c2*cfcW^T + cfcb ----
  P = GArgs{};
  P.j[0] = { h2h, hfch, nullptr, hp3h, hfcb, nullptr, h1f, 768, 768, 0 };
  P.j[1] = { c2h, cfch, cp3f, nullptr, cfcb, nullptr, c1f, 768, 768, 0 };
  gemm_k<<<dim3(6, 16, 2), 256, 0, stream>>>(P);

  // ---- 5. cell3: gates = [x|hp3]*[Wih3|Whh2]^T + bih3 + bhh3 ----
  cell_k<<<dim3(24, 16), 256, 0, stream>>>(xh, hp3h,
      Wihh + (size_t)6144 * 768, Whhh + 2359296,
      bih + 6144, bhh + 6144, cp3f, h3f, nullptr, nullptr, nullptr, 48);

  // ---- 6. fused attention (single pass over attn) ----
  attn_k<<<1024, 256, 0, stream>>>(attn, h1f, h2f, h3f, a1h, a2h, a3h);

  // ---- 7. heads: m = relu(a*midW^T + midb), 3 tasks batched ----
  P = GArgs{};
  P.j[0] = { a1h, midh,           nullptr, m1h, midb,        nullptr, nullptr, 768, 768, 1 };
  P.j[1] = { a2h, midh +  589824, nullptr, m2h, midb +  768, nullptr, nullptr, 768, 768, 1 };
  P.j[2] = { a3h, midh + 1179648, nullptr, m3h, midb + 1536, nullptr, nullptr, 768, 768, 1 };
  gemm_k<<<dim3(6, 16, 3), 256, 0, stream>>>(P);

  // ---- 8. output heads, 3 tasks batched ----
  P = GArgs{};
  P.j[0] = { m1h, o1h, out,          nullptr, o1b, nullptr, nullptr, 202, 202, 0 };
  P.j[1] = { m2h, o2h, out + 206848, nullptr, o2b, nullptr, nullptr, 183, 183, 0 };
  P.j[2] = { m3h, o3h, out + 394240, nullptr, o3b, nullptr, nullptr,  11,  11, 0 };
  gemm_k<<<dim3(2, 16, 3), 256, 0, stream>>>(P);

  (void)in_sizes; (void)n_in; (void)out_size; (void)ws_size;
}